// Round 11
// baseline (654.766 us; speedup 1.0000x reference)
//
#include <hip/hip_runtime.h>
#include <hip/hip_bf16.h>

#define N_    8
#define H_    32
#define W_    32
#define C_    768
#define NH_   12
#define HD_   64
#define B_    96      // N_*NH_
#define HW_   1024
#define C3_   2304
#define SCALE_ 0.125f
#define LOG2E_ 1.4426950408889634f

typedef __attribute__((ext_vector_type(4))) float f32x4;
typedef __attribute__((ext_vector_type(16))) float f32x16;
typedef __attribute__((ext_vector_type(8))) short s16x8;
typedef __attribute__((ext_vector_type(2))) int i32x2;
typedef __attribute__((ext_vector_type(4))) unsigned int u32x4;
typedef unsigned short u16;
typedef unsigned int u32;

__device__ inline u16 f2b(float x) {
    __hip_bfloat16 h = __float2bfloat16(x);
    return *reinterpret_cast<u16*>(&h);
}
__device__ inline float b2f(u16 x) {
    u32 u = ((u32)x) << 16;
    return *reinterpret_cast<float*>(&u);
}

__device__ __forceinline__ void gld_lds16(const void* g, void* l) {
    __builtin_amdgcn_global_load_lds(
        (const __attribute__((address_space(1))) u32*)g,
        (__attribute__((address_space(3))) u32*)l, 16, 0, 0);
}

// ---------------------------------------------------------------------------
// convert fp32 -> bf16 (vectorized, grid-stride)
// ---------------------------------------------------------------------------
__global__ __launch_bounds__(256) void cvt_bf16(const float* __restrict__ in,
                                                u16* __restrict__ out, int n4) {
    for (int i = blockIdx.x * blockDim.x + threadIdx.x; i < n4; i += gridDim.x * blockDim.x) {
        float4 v = ((const float4*)in)[i];
        ushort4 o;
        o.x = f2b(v.x); o.y = f2b(v.y); o.z = f2b(v.z); o.w = f2b(v.w);
        ((ushort4*)out)[i] = o;
    }
}

// ---------------------------------------------------------------------------
// transpose-convert: in [K][N] fp32 -> out [N][K] bf16, 64x64 tiles
// ---------------------------------------------------------------------------
__global__ __launch_bounds__(256) void tcvt_bf16(const float* __restrict__ in,
                                                 u16* __restrict__ out, int K, int N) {
    __shared__ u16 tile[64][72];
    const int t = threadIdx.x;
    const int k0 = blockIdx.y * 64, n0 = blockIdx.x * 64;
    const int r = t >> 2, c4 = (t & 3) * 16;
    #pragma unroll
    for (int u = 0; u < 4; ++u) {
        float4 v = *(const float4*)(in + (size_t)(k0 + r) * N + n0 + c4 + u * 4);
        tile[c4 + u*4 + 0][r] = f2b(v.x);
        tile[c4 + u*4 + 1][r] = f2b(v.y);
        tile[c4 + u*4 + 2][r] = f2b(v.z);
        tile[c4 + u*4 + 3][r] = f2b(v.w);
    }
    __syncthreads();
    #pragma unroll
    for (int u = 0; u < 2; ++u) {
        s16x8 v;
        #pragma unroll
        for (int e = 0; e < 8; ++e) v[e] = (short)tile[r][c4 + u*8 + e];
        *(s16x8*)(out + (size_t)(n0 + r) * K + k0 + c4 + u*8) = v;
    }
}

// ---------------------------------------------------------------------------
// MFMA GEMM core (m97-style): 128x128 tile, BK=32, 4 waves 2x2, double-buffered
// LDS via global_load_lds width 16, one barrier per K-step. K = 768.
// ---------------------------------------------------------------------------
#define GEMM_CORE(A_, Bt_)                                                           \
    __shared__ u16 sA[2][128 * 32];                                                  \
    __shared__ u16 sB[2][128 * 32];                                                  \
    const int t = threadIdx.x;                                                       \
    const int lane = t & 63;                                                         \
    const int w = t >> 6;                                                            \
    const int wm = w >> 1, wn = w & 1;                                               \
    const int l15 = lane & 15, lg = lane >> 4;                                       \
    const int nbase = blockIdx.x * 128;                                              \
    const int mbase = blockIdx.y * 128;                                              \
    const int srow = lane >> 2;                                                      \
    const int sslot = lane & 3;                                                      \
    const u16* gA0 = (A_) + (size_t)(mbase + w * 16 + srow) * 768 + sslot * 8;       \
    const u16* gA1 = gA0 + (size_t)64 * 768;                                         \
    const u16* gB0 = (Bt_) + (size_t)(nbase + w * 16 + srow) * 768 + sslot * 8;      \
    const u16* gB1 = gB0 + (size_t)64 * 768;                                         \
    f32x4 acc[4][4] = {};                                                            \
    gld_lds16(gA0, &sA[0][w * 512]);                                                 \
    gld_lds16(gA1, &sA[0][(w + 4) * 512]);                                           \
    gld_lds16(gB0, &sB[0][w * 512]);                                                 \
    gld_lds16(gB1, &sB[0][(w + 4) * 512]);                                           \
    for (int kt = 0; kt < 24; ++kt) {                                                \
        const int p = kt & 1;                                                        \
        __syncthreads();                                                             \
        if (kt < 23) {                                                               \
            const int kb = (kt + 1) * 32;                                            \
            gld_lds16(gA0 + kb, &sA[p ^ 1][w * 512]);                                \
            gld_lds16(gA1 + kb, &sA[p ^ 1][(w + 4) * 512]);                          \
            gld_lds16(gB0 + kb, &sB[p ^ 1][w * 512]);                                \
            gld_lds16(gB1 + kb, &sB[p ^ 1][(w + 4) * 512]);                          \
        }                                                                            \
        const u16* pa = &sA[p][(wm * 64 + l15) * 32 + lg * 8];                       \
        const u16* pb = &sB[p][(wn * 64 + l15) * 32 + lg * 8];                       \
        s16x8 afr[4], bfr[4];                                                        \
        _Pragma("unroll")                                                            \
        for (int i = 0; i < 4; ++i) {                                                \
            afr[i] = *(const s16x8*)(pa + i * 512);                                  \
            bfr[i] = *(const s16x8*)(pb + i * 512);                                  \
        }                                                                            \
        _Pragma("unroll")                                                            \
        for (int i = 0; i < 4; ++i)                                                  \
            _Pragma("unroll")                                                        \
            for (int j = 0; j < 4; ++j)                                              \
                acc[i][j] = __builtin_amdgcn_mfma_f32_16x16x32_bf16(afr[i], bfr[j],  \
                                                                    acc[i][j], 0, 0, 0); \
    }

__global__ __launch_bounds__(256) void gemm_qkv(const u16* __restrict__ A,
                                                const u16* __restrict__ Bt,
                                                const float* __restrict__ bias,
                                                float* __restrict__ qout,
                                                u16* __restrict__ kout,
                                                u16* __restrict__ vout) {
    GEMM_CORE(A, Bt)
    const int which = nbase / C_;
    const int head  = ((nbase % C_) >> 6) + wn;
    const int mrow0 = mbase + wm * 64 + lg * 4;
    #pragma unroll
    for (int i = 0; i < 4; ++i) {
        #pragma unroll
        for (int r = 0; r < 4; ++r) {
            const int m = mrow0 + i * 16 + r;
            const size_t bidx = (size_t)((m >> 10) * NH_ + head);
            const int pp = m & 1023;
            #pragma unroll
            for (int j = 0; j < 4; ++j) {
                const int d = j * 16 + l15;
                const float val = acc[i][j][r] + bias[nbase + wn * 64 + d];
                if (which == 0)      qout[(bidx * HW_ + pp) * HD_ + d] = val;
                else if (which == 1) kout[(bidx * HW_ + pp) * HD_ + d] = f2b(val);
                else                 vout[bidx * (size_t)(HW_ * HD_) + (size_t)d * HW_ + pp] = f2b(val);
            }
        }
    }
}

__global__ __launch_bounds__(256) void gemm_proj(const u16* __restrict__ A,
                                                 const u16* __restrict__ Bt,
                                                 const float* __restrict__ bias,
                                                 float* __restrict__ out) {
    GEMM_CORE(A, Bt)
    const int mrow0 = mbase + wm * 64 + lg * 4;
    #pragma unroll
    for (int i = 0; i < 4; ++i) {
        #pragma unroll
        for (int r = 0; r < 4; ++r) {
            const int m = mrow0 + i * 16 + r;
            #pragma unroll
            for (int j = 0; j < 4; ++j) {
                const int n = nbase + wn * 64 + j * 16 + l15;
                out[(size_t)m * C_ + n] = acc[i][j][r] + bias[n];
            }
        }
    }
}

// ---------------------------------------------------------------------------
// Kernel: attn with KV-SPLIT 2 (flash-decoding style).
// Block = (b, 128 q-rows, 512-kv half); grid 1536 = 6 blocks/CU, 24 waves/CU.
// Inner loop byte-identical to round 10 (32x32 swapped QK^T, permlane P,
// exp2-folded bias, reg-staged prefetch, 2 barriers per 64-kv tile), 8 iters.
// Max-free softmax -> partials combine exactly: Po (unnormalized f32 O) and
// lsum per split, reduced by attn_combine.
// Bias prologue rebuilt: rel tables staged to padded LDS phase-by-phase
// (rel_h 19 rows for this split's 16 kh cols; then rel_w 63 rows), Q read
// from global (L1-hot), bw computed per-lane with Q-chunk reuse.
// LDS: sBH u16[128][18] @0 (4608, persistent); sK u16[64][72] @4608;
//   sVt u16[64][72] @13824 (end 23040); relL f32[63][68] @4608 (transient,
//   17136 <= 18432).  23040 B -> 7 blocks/CU capacity, 6 resident.
// ---------------------------------------------------------------------------
__global__ __launch_bounds__(256, 6) void attn_mfma(const float* __restrict__ qf,
                                                    const u16* __restrict__ kbf,
                                                    const u16* __restrict__ vtb,
                                                    const float* __restrict__ rel_h,
                                                    const float* __restrict__ rel_w,
                                                    float* __restrict__ Po,
                                                    float* __restrict__ ls) {
    extern __shared__ char smem[];
    u16*   sBH  = (u16*)smem;                 // [128][18] bf16 (persistent)
    u16*   sK   = (u16*)(smem + 4608);        // [64][72]
    u16*   sVt  = (u16*)(smem + 13824);       // [64][72]
    float* relL = (float*)(smem + 4608);      // [63][68] f32 (prologue only)

    const int t = threadIdx.x;
    const int lane = t & 63;
    const int w = t >> 6;
    const int l31 = lane & 31;
    const int hi  = lane >> 5;
    const int qw  = w * 32;

    // XCD-bijective swizzle: 1536 blocks, 192/XCD = 12 whole b's
    const int bid = blockIdx.x;
    const int swz = (bid & 7) * 192 + (bid >> 3);
    const int b = swz >> 4;
    const int rem = swz & 15;
    const int qbase = (rem >> 1) * 128;
    const int split = rem & 1;
    const int kvbase = split * 512;
    const int K0 = split * 16;                // kh column base

    // ---- Q fragments (B-operand of swapped QK^T), pre-scaled by SCALE*log2e
    s16x8 qfr[4];
    {
        const float* qrow = qf + ((size_t)b * HW_ + qbase + qw + l31) * HD_;
        #pragma unroll
        for (int ck = 0; ck < 4; ++ck) {
            float4 x0 = *(const float4*)(qrow + ck * 16 + hi * 8);
            float4 x1 = *(const float4*)(qrow + ck * 16 + hi * 8 + 4);
            qfr[ck][0] = (short)f2b(x0.x * (SCALE_ * LOG2E_));
            qfr[ck][1] = (short)f2b(x0.y * (SCALE_ * LOG2E_));
            qfr[ck][2] = (short)f2b(x0.z * (SCALE_ * LOG2E_));
            qfr[ck][3] = (short)f2b(x0.w * (SCALE_ * LOG2E_));
            qfr[ck][4] = (short)f2b(x1.x * (SCALE_ * LOG2E_));
            qfr[ck][5] = (short)f2b(x1.y * (SCALE_ * LOG2E_));
            qfr[ck][6] = (short)f2b(x1.z * (SCALE_ * LOG2E_));
            qfr[ck][7] = (short)f2b(x1.w * (SCALE_ * LOG2E_));
        }
    }

    // ==== Phase A: bh table for this split's 16 kh columns ====
    // rel_h rows needed: idx = (q>>5) - kh + 31, q-group A..A+3, kh K0..K0+15
    // -> 19 consecutive rows starting at rbase = A - K0 + 16.
    const int Agrp = qbase >> 5;
    const int rbase = Agrp - K0 + 16;
    for (int i2 = t; i2 < 19 * 16; i2 += 256) {
        const int row = i2 >> 4;
        const int c4 = (i2 & 15) * 4;
        *(float4*)(relL + row * 68 + c4) = *(const float4*)(rel_h + (size_t)(rbase + row) * HD_ + c4);
    }
    __syncthreads();
    for (int idv = t; idv < 2048; idv += 256) {     // 128 rows x 16 kh
        const int row = idv >> 4;
        const int j   = idv & 15;
        const int lidx = (row >> 5) - j + 15;       // local rel_h row
        const float* rp = relL + lidx * 68;
        const float* qv = qf + ((size_t)b * HW_ + qbase + row) * HD_;
        float acc = 0.f;
        #pragma unroll
        for (int d4 = 0; d4 < 16; ++d4) {
            float4 r4 = *(const float4*)(rp + d4 * 4);
            float4 q4 = *(const float4*)(qv + d4 * 4);
            acc += q4.x*r4.x + q4.y*r4.y + q4.z*r4.z + q4.w*r4.w;
        }
        sBH[row * 18 + j] = f2b(acc * LOG2E_);
    }
    __syncthreads();

    // ==== Phase B: bw per-lane (16 values), rel_w staged to LDS ====
    for (int i2 = t; i2 < 63 * 16; i2 += 256) {
        const int row = i2 >> 4;
        const int c4 = (i2 & 15) * 4;
        *(float4*)(relL + row * 68 + c4) = *(const float4*)(rel_w + (size_t)row * HD_ + c4);
    }
    __syncthreads();
    f32x4 bwv[4];
    {
        float bwacc[16] = {};
        int idxs[16];
        #pragma unroll
        for (int m = 0; m < 4; ++m)
            #pragma unroll
            for (int jj = 0; jj < 4; ++jj)
                idxs[m * 4 + jj] = l31 - (m * 8 + hi * 4 + jj) + 31;
        const float* qrow = qf + ((size_t)b * HW_ + qbase + qw + l31) * HD_;
        for (int c4 = 0; c4 < 16; ++c4) {
            float4 q4 = *(const float4*)(qrow + c4 * 4);
            #pragma unroll
            for (int e = 0; e < 16; ++e) {
                float4 r4 = *(const float4*)(relL + idxs[e] * 68 + c4 * 4);
                bwacc[e] += q4.x*r4.x + q4.y*r4.y + q4.z*r4.z + q4.w*r4.w;
            }
        }
        #pragma unroll
        for (int m = 0; m < 4; ++m)
            #pragma unroll
            for (int jj = 0; jj < 4; ++jj)
                bwv[m][jj] = bwacc[m * 4 + jj] * LOG2E_;
    }
    __syncthreads();   // relL dead; sK/sVt writable

    // ---- staging geometry (r8/r10-verified mapping, pad-72 rows)
    const int srow = t >> 2;
    const int sc0  = (t & 3) * 16;
    const u16* kg = kbf + ((size_t)b * HW_ + kvbase + srow) * HD_ + sc0;
    const u16* vg = vtb + (size_t)b * HD_ * HW_ + (size_t)srow * HW_ + kvbase + sc0;
    u16* skw = sK  + srow * 72 + sc0;
    u16* svw = sVt + srow * 72 + sc0;

    // ---- preload tile 0
    s16x8 kr0 = *(const s16x8*)(kg);
    s16x8 kr1 = *(const s16x8*)(kg + 8);
    s16x8 vr0 = *(const s16x8*)(vg);
    s16x8 vr1 = *(const s16x8*)(vg + 8);
    *(s16x8*)(skw)     = kr0;
    *(s16x8*)(skw + 8) = kr1;
    *(s16x8*)(svw)     = vr0;
    *(s16x8*)(svw + 8) = vr1;
    __syncthreads();   // sK(0)/sVt(0) ready

    f32x16 Oacc[2] = {};
    float lsum = 0.f;
    const int bhbase = (qw + l31) * 18;

    for (int kt = 0; kt < 8; ++kt) {
        if (kt < 7) {
            const u16* kn = kg + (size_t)(kt + 1) * 64 * HD_;
            kr0 = *(const s16x8*)(kn);
            kr1 = *(const s16x8*)(kn + 8);
            const u16* vn = vg + (size_t)(kt + 1) * 64;
            vr0 = *(const s16x8*)(vn);
            vr1 = *(const s16x8*)(vn + 8);
        }

        const float bh0 = b2f(sBH[bhbase + 2 * kt]);
        const float bh1 = b2f(sBH[bhbase + 2 * kt + 1]);

        #pragma unroll
        for (int kvt = 0; kvt < 2; ++kvt) {
            f32x16 s = {};
            #pragma unroll
            for (int ck = 0; ck < 4; ++ck) {
                s16x8 kf = *(const s16x8*)(sK + (kvt * 32 + l31) * 72 + ck * 16 + hi * 8);
                s = __builtin_amdgcn_mfma_f32_32x32x16_bf16(kf, qfr[ck], s, 0, 0, 0);
            }
            const float bh = kvt ? bh1 : bh0;

            u32 pw[8];
            #pragma unroll
            for (int m = 0; m < 8; ++m) {
                float p0 = __builtin_amdgcn_exp2f(s[2*m]   + bh + bwv[(2*m)>>2][(2*m)&3]);
                float p1 = __builtin_amdgcn_exp2f(s[2*m+1] + bh + bwv[(2*m+1)>>2][(2*m+1)&3]);
                lsum += p0 + p1;
                pw[m] = (u32)f2b(p0) | ((u32)f2b(p1) << 16);
            }

            #pragma unroll
            for (int cc = 0; cc < 2; ++cc) {
                i32x2 s02 = __builtin_amdgcn_permlane32_swap((int)pw[cc*4+0], (int)pw[cc*4+2], false, false);
                i32x2 s13 = __builtin_amdgcn_permlane32_swap((int)pw[cc*4+1], (int)pw[cc*4+3], false, false);
                u32x4 pau;
                pau.x = (u32)s02.x; pau.y = (u32)s13.x;
                pau.z = (u32)s02.y; pau.w = (u32)s13.y;
                s16x8 pa = *reinterpret_cast<s16x8*>(&pau);
                const int kc = kvt * 2 + cc;
                #pragma unroll
                for (int dt = 0; dt < 2; ++dt) {
                    s16x8 vf = *(const s16x8*)(sVt + (dt * 32 + l31) * 72 + kc * 16 + hi * 8);
                    Oacc[dt] = __builtin_amdgcn_mfma_f32_32x32x16_bf16(pa, vf, Oacc[dt], 0, 0, 0);
                }
            }
        }

        __syncthreads();   // B1
        if (kt < 7) {
            *(s16x8*)(skw)     = kr0;
            *(s16x8*)(skw + 8) = kr1;
            *(s16x8*)(svw)     = vr0;
            *(s16x8*)(svw + 8) = vr1;
        }
        __syncthreads();   // B2
    }

    // ---- epilogue: store UNNORMALIZED partials
    float lsumF = lsum + __shfl_xor(lsum, 32);   // full split-sum for q = qw+l31
    const size_t srow0 = ((size_t)(split * B_ + b) * HW_);
    if (hi == 0)
        ls[srow0 + qbase + qw + l31] = lsumF;
    float* po = Po + srow0 * HD_;
    #pragma unroll
    for (int dt = 0; dt < 2; ++dt) {
        #pragma unroll
        for (int r = 0; r < 16; ++r) {
            const int qloc = (r & 3) + 8 * (r >> 2) + 4 * hi;
            const int qg = qbase + qw + qloc;
            po[(size_t)qg * HD_ + dt * 32 + l31] = Oacc[dt][r];
        }
    }
}

// ---------------------------------------------------------------------------
// Combine: out = (Po0 + Po1) / (ls0 + ls1), written as bf16 [m][c].
// ---------------------------------------------------------------------------
__global__ __launch_bounds__(256) void attn_combine(const float* __restrict__ Po,
                                                    const float* __restrict__ ls,
                                                    u16* __restrict__ ob) {
    const int i = blockIdx.x * 256 + threadIdx.x;   // B_*HW_*16
    const int row = i >> 4;                         // b*1024 + q
    const int d4 = (i & 15) * 4;
    const size_t seg = (size_t)B_ * HW_;
    float4 a = *(const float4*)(Po + (size_t)row * HD_ + d4);
    float4 c = *(const float4*)(Po + (seg + row) * HD_ + d4);
    const float inv = 1.0f / (ls[row] + ls[seg + row]);
    const int b = row >> 10, q = row & 1023;
    const int n_img = b / NH_, head = b % NH_;
    ushort4 o;
    o.x = f2b((a.x + c.x) * inv);
    o.y = f2b((a.y + c.y) * inv);
    o.z = f2b((a.z + c.z) * inv);
    o.w = f2b((a.w + c.w) * inv);
    *(ushort4*)(ob + (size_t)(n_img * HW_ + q) * C_ + head * HD_ + d4) = o;
}

extern "C" void kernel_launch(void* const* d_in, const int* in_sizes, int n_in,
                              void* d_out, int out_size, void* d_ws, size_t ws_size,
                              hipStream_t stream) {
    const float* x      = (const float*)d_in[0];
    const float* w_qkv  = (const float*)d_in[1];
    const float* b_qkv  = (const float*)d_in[2];
    const float* w_proj = (const float*)d_in[3];
    const float* b_proj = (const float*)d_in[4];
    const float* rel_h  = (const float*)d_in[5];
    const float* rel_w  = (const float*)d_in[6];
    float* out = (float*)d_out;

    const size_t seg = (size_t)B_ * HW_ * HD_;   // 6,291,456
    char* p = (char*)d_ws;
    u16* xb     = (u16*)p;  p += seg * 2;
    u16* wqkvT  = (u16*)p;  p += (size_t)C3_ * C_ * 2;
    u16* wprojT = (u16*)p;  p += (size_t)C_ * C_ * 2;
    float* qfp  = (float*)p; p += seg * 4;
    u16* kbf    = (u16*)p;  p += seg * 2;
    u16* vtb    = (u16*)p;  p += seg * 2;
    u16* ob     = (u16*)p;  p += seg * 2;
    float* Po   = (float*)p; p += 2 * seg * 4;                   // 50.3 MB
    float* ls   = (float*)p; p += 2 * (size_t)B_ * HW_ * 4;      // 0.8 MB

    cvt_bf16<<<2048, 256, 0, stream>>>(x, xb, (int)(seg / 4));
    tcvt_bf16<<<dim3(C3_ / 64, C_ / 64), 256, 0, stream>>>(w_qkv, wqkvT, C_, C3_);
    tcvt_bf16<<<dim3(C_ / 64, C_ / 64), 256, 0, stream>>>(w_proj, wprojT, C_, C_);

    gemm_qkv<<<dim3(C3_ / 128, 8192 / 128), 256, 0, stream>>>(xb, wqkvT, b_qkv, qfp, kbf, vtb);
    attn_mfma<<<1536, 256, 23040, stream>>>(qfp, kbf, vtb, rel_h, rel_w, Po, ls);
    attn_combine<<<(B_ * HW_ * 16) / 256, 256, 0, stream>>>(Po, ls, ob);
    gemm_proj<<<dim3(C_ / 128, 8192 / 128), 256, 0, stream>>>(ob, wprojT, b_proj, out);
}

// Round 12
// 493.586 us; speedup vs baseline: 1.3266x; 1.3266x over previous
//
#include <hip/hip_runtime.h>
#include <hip/hip_bf16.h>

#define N_    8
#define H_    32
#define W_    32
#define C_    768
#define NH_   12
#define HD_   64
#define B_    96      // N_*NH_
#define HW_   1024
#define C3_   2304
#define SCALE_ 0.125f
#define LOG2E_ 1.4426950408889634f

typedef __attribute__((ext_vector_type(4))) float f32x4;
typedef __attribute__((ext_vector_type(16))) float f32x16;
typedef __attribute__((ext_vector_type(8))) short s16x8;
typedef __attribute__((ext_vector_type(2))) int i32x2;
typedef __attribute__((ext_vector_type(4))) unsigned int u32x4;
typedef unsigned short u16;
typedef unsigned int u32;

__device__ inline u16 f2b(float x) {
    __hip_bfloat16 h = __float2bfloat16(x);
    return *reinterpret_cast<u16*>(&h);
}
__device__ inline float b2f(u16 x) {
    u32 u = ((u32)x) << 16;
    return *reinterpret_cast<float*>(&u);
}

__device__ __forceinline__ void gld_lds16(const void* g, void* l) {
    __builtin_amdgcn_global_load_lds(
        (const __attribute__((address_space(1))) u32*)g,
        (__attribute__((address_space(3))) u32*)l, 16, 0, 0);
}

// ---------------------------------------------------------------------------
// convert fp32 -> bf16 (vectorized, grid-stride)
// ---------------------------------------------------------------------------
__global__ __launch_bounds__(256) void cvt_bf16(const float* __restrict__ in,
                                                u16* __restrict__ out, int n4) {
    for (int i = blockIdx.x * blockDim.x + threadIdx.x; i < n4; i += gridDim.x * blockDim.x) {
        float4 v = ((const float4*)in)[i];
        ushort4 o;
        o.x = f2b(v.x); o.y = f2b(v.y); o.z = f2b(v.z); o.w = f2b(v.w);
        ((ushort4*)out)[i] = o;
    }
}

// ---------------------------------------------------------------------------
// transpose-convert: in [K][N] fp32 -> out [N][K] bf16, 64x64 tiles
// ---------------------------------------------------------------------------
__global__ __launch_bounds__(256) void tcvt_bf16(const float* __restrict__ in,
                                                 u16* __restrict__ out, int K, int N) {
    __shared__ u16 tile[64][72];
    const int t = threadIdx.x;
    const int k0 = blockIdx.y * 64, n0 = blockIdx.x * 64;
    const int r = t >> 2, c4 = (t & 3) * 16;
    #pragma unroll
    for (int u = 0; u < 4; ++u) {
        float4 v = *(const float4*)(in + (size_t)(k0 + r) * N + n0 + c4 + u * 4);
        tile[c4 + u*4 + 0][r] = f2b(v.x);
        tile[c4 + u*4 + 1][r] = f2b(v.y);
        tile[c4 + u*4 + 2][r] = f2b(v.z);
        tile[c4 + u*4 + 3][r] = f2b(v.w);
    }
    __syncthreads();
    #pragma unroll
    for (int u = 0; u < 2; ++u) {
        s16x8 v;
        #pragma unroll
        for (int e = 0; e < 8; ++e) v[e] = (short)tile[r][c4 + u*8 + e];
        *(s16x8*)(out + (size_t)(n0 + r) * K + k0 + c4 + u*8) = v;
    }
}

// ---------------------------------------------------------------------------
// MFMA GEMM core (m97-style): 128x128 tile, BK=32, 4 waves 2x2, double-buffered
// LDS via global_load_lds width 16, one barrier per K-step. K = 768.
// ---------------------------------------------------------------------------
#define GEMM_CORE(A_, Bt_)                                                           \
    __shared__ u16 sA[2][128 * 32];                                                  \
    __shared__ u16 sB[2][128 * 32];                                                  \
    const int t = threadIdx.x;                                                       \
    const int lane = t & 63;                                                         \
    const int w = t >> 6;                                                            \
    const int wm = w >> 1, wn = w & 1;                                               \
    const int l15 = lane & 15, lg = lane >> 4;                                       \
    const int nbase = blockIdx.x * 128;                                              \
    const int mbase = blockIdx.y * 128;                                              \
    const int srow = lane >> 2;                                                      \
    const int sslot = lane & 3;                                                      \
    const u16* gA0 = (A_) + (size_t)(mbase + w * 16 + srow) * 768 + sslot * 8;       \
    const u16* gA1 = gA0 + (size_t)64 * 768;                                         \
    const u16* gB0 = (Bt_) + (size_t)(nbase + w * 16 + srow) * 768 + sslot * 8;      \
    const u16* gB1 = gB0 + (size_t)64 * 768;                                         \
    f32x4 acc[4][4] = {};                                                            \
    gld_lds16(gA0, &sA[0][w * 512]);                                                 \
    gld_lds16(gA1, &sA[0][(w + 4) * 512]);                                           \
    gld_lds16(gB0, &sB[0][w * 512]);                                                 \
    gld_lds16(gB1, &sB[0][(w + 4) * 512]);                                           \
    for (int kt = 0; kt < 24; ++kt) {                                                \
        const int p = kt & 1;                                                        \
        __syncthreads();                                                             \
        if (kt < 23) {                                                               \
            const int kb = (kt + 1) * 32;                                            \
            gld_lds16(gA0 + kb, &sA[p ^ 1][w * 512]);                                \
            gld_lds16(gA1 + kb, &sA[p ^ 1][(w + 4) * 512]);                          \
            gld_lds16(gB0 + kb, &sB[p ^ 1][w * 512]);                                \
            gld_lds16(gB1 + kb, &sB[p ^ 1][(w + 4) * 512]);                          \
        }                                                                            \
        const u16* pa = &sA[p][(wm * 64 + l15) * 32 + lg * 8];                       \
        const u16* pb = &sB[p][(wn * 64 + l15) * 32 + lg * 8];                       \
        s16x8 afr[4], bfr[4];                                                        \
        _Pragma("unroll")                                                            \
        for (int i = 0; i < 4; ++i) {                                                \
            afr[i] = *(const s16x8*)(pa + i * 512);                                  \
            bfr[i] = *(const s16x8*)(pb + i * 512);                                  \
        }                                                                            \
        _Pragma("unroll")                                                            \
        for (int i = 0; i < 4; ++i)                                                  \
            _Pragma("unroll")                                                        \
            for (int j = 0; j < 4; ++j)                                              \
                acc[i][j] = __builtin_amdgcn_mfma_f32_16x16x32_bf16(afr[i], bfr[j],  \
                                                                    acc[i][j], 0, 0, 0); \
    }

__global__ __launch_bounds__(256) void gemm_qkv(const u16* __restrict__ A,
                                                const u16* __restrict__ Bt,
                                                const float* __restrict__ bias,
                                                float* __restrict__ qout,
                                                u16* __restrict__ kout,
                                                u16* __restrict__ vout) {
    GEMM_CORE(A, Bt)
    const int which = nbase / C_;
    const int head  = ((nbase % C_) >> 6) + wn;
    const int mrow0 = mbase + wm * 64 + lg * 4;
    #pragma unroll
    for (int i = 0; i < 4; ++i) {
        #pragma unroll
        for (int r = 0; r < 4; ++r) {
            const int m = mrow0 + i * 16 + r;
            const size_t bidx = (size_t)((m >> 10) * NH_ + head);
            const int pp = m & 1023;
            #pragma unroll
            for (int j = 0; j < 4; ++j) {
                const int d = j * 16 + l15;
                const float val = acc[i][j][r] + bias[nbase + wn * 64 + d];
                if (which == 0)      qout[(bidx * HW_ + pp) * HD_ + d] = val;
                else if (which == 1) kout[(bidx * HW_ + pp) * HD_ + d] = f2b(val);
                else                 vout[bidx * (size_t)(HW_ * HD_) + (size_t)d * HW_ + pp] = f2b(val);
            }
        }
    }
}

__global__ __launch_bounds__(256) void gemm_proj(const u16* __restrict__ A,
                                                 const u16* __restrict__ Bt,
                                                 const float* __restrict__ bias,
                                                 float* __restrict__ out) {
    GEMM_CORE(A, Bt)
    const int mrow0 = mbase + wm * 64 + lg * 4;
    #pragma unroll
    for (int i = 0; i < 4; ++i) {
        #pragma unroll
        for (int r = 0; r < 4; ++r) {
            const int m = mrow0 + i * 16 + r;
            #pragma unroll
            for (int j = 0; j < 4; ++j) {
                const int n = nbase + wn * 64 + j * 16 + l15;
                out[(size_t)m * C_ + n] = acc[i][j][r] + bias[n];
            }
        }
    }
}

// ---------------------------------------------------------------------------
// Kernel: attn with FUSED kv-split-2: 512 threads = 8 waves.
// Waves 0-3 (group 0) process kv [0,512); waves 4-7 (group 1) kv [512,1024);
// both cover the same 128 q-rows. Inner loop per group is byte-identical to
// round 10 (32x32 swapped QK^T, permlane P, exp2-folded bias, reg-staged
// prefetch, 2 barriers per 64-kv tile), 8 iterations on group-private
// sK/sVt buffers. Max-free softmax -> exact combine: group 1 pushes
// unnormalized Oacc + lsum through LDS; group 0 adds, normalizes, stores.
// grid 768 = 96 b x 8 q-tiles; 45568 B LDS -> 3 blocks/CU = 24 waves/CU
// (6 waves/SIMD, vs 4 in round 10).  __launch_bounds__(512,5): VGPR cap 102
// (round-10 body measured 64 -> no spill).
// LDS map (bytes):
//   sBH  u16[128][34] @0      (8704, persistent; kh = g*16 + 2kt + kvt)
//   sK0 @8704  sK1 @17920  sVt0 @27136  sVt1 @36352   (each u16[64][72])
//   qs   f32[64][68] @8704  (prologue transient)
//   sBW  f32[64][36] @26112 (prologue transient)
//   exch f32[128][68] @8704 (epilogue transient, 34816)
//   lsumX f32[128] @43520   (epilogue transient)
// total 45568.
// ---------------------------------------------------------------------------
__global__ __launch_bounds__(512, 5) void attn_mfma(const float* __restrict__ qf,
                                                    const u16* __restrict__ kbf,
                                                    const u16* __restrict__ vtb,
                                                    const float* __restrict__ rel_h,
                                                    const float* __restrict__ rel_w,
                                                    u16* __restrict__ ob) {
    extern __shared__ char smem[];
    u16*   sBH  = (u16*)smem;                 // [128][34] bf16 (persistent)
    float* qs   = (float*)(smem + 8704);      // [64][68] f32 (prologue only)
    float* sBW  = (float*)(smem + 26112);     // [64][36] f32 (prologue only)
    float* exch = (float*)(smem + 8704);      // [128][68] f32 (epilogue only)
    float* lsumX= (float*)(smem + 43520);     // [128] f32 (epilogue only)

    const int t = threadIdx.x;
    const int lane = t & 63;
    const int g  = t >> 8;                    // kv-split group 0/1
    const int wg = (t >> 6) & 3;              // wave within group
    const int l31 = lane & 31;
    const int hi  = lane >> 5;
    const int qw  = wg * 32;

    u16* sK  = (u16*)(smem + 8704  + g * 9216);   // group-private
    u16* sVt = (u16*)(smem + 27136 + g * 9216);

    // XCD-bijective swizzle: 768 blocks, 96 per XCD = 12 whole b's
    const int bid = blockIdx.x;
    const int swz = (bid & 7) * 96 + (bid >> 3);
    const int b = swz >> 3;
    const int qbase = (swz & 7) * 128;

    // ---- Q fragments (B-operand of swapped QK^T), pre-scaled by SCALE*log2e
    s16x8 qfr[4];
    {
        const float* qrow = qf + ((size_t)b * HW_ + qbase + qw + l31) * HD_;
        #pragma unroll
        for (int ck = 0; ck < 4; ++ck) {
            float4 x0 = *(const float4*)(qrow + ck * 16 + hi * 8);
            float4 x1 = *(const float4*)(qrow + ck * 16 + hi * 8 + 4);
            qfr[ck][0] = (short)f2b(x0.x * (SCALE_ * LOG2E_));
            qfr[ck][1] = (short)f2b(x0.y * (SCALE_ * LOG2E_));
            qfr[ck][2] = (short)f2b(x0.z * (SCALE_ * LOG2E_));
            qfr[ck][3] = (short)f2b(x0.w * (SCALE_ * LOG2E_));
            qfr[ck][4] = (short)f2b(x1.x * (SCALE_ * LOG2E_));
            qfr[ck][5] = (short)f2b(x1.y * (SCALE_ * LOG2E_));
            qfr[ck][6] = (short)f2b(x1.z * (SCALE_ * LOG2E_));
            qfr[ck][7] = (short)f2b(x1.w * (SCALE_ * LOG2E_));
        }
    }

    // ---- bias tables in two 64-row passes (x log2e); bw hoisted to regs.
    // (round-10-verified math, strides adapted to 512 threads)
    f32x4 bwv[4];
    for (int p = 0; p < 2; ++p) {
        {   // stage qs rows [p*64, p*64+64) (fp32, exact)
            const int row = t >> 3;
            const int c0 = (t & 7) * 8;
            const float* src = qf + ((size_t)b * HW_ + qbase + p * 64 + row) * HD_ + c0;
            float4 v0 = *(const float4*)(src);
            float4 v1 = *(const float4*)(src + 4);
            float* qd = qs + row * 68 + c0;
            qd[0] = v0.x; qd[1] = v0.y; qd[2] = v0.z; qd[3] = v0.w;
            qd[4] = v1.x; qd[5] = v1.y; qd[6] = v1.z; qd[7] = v1.w;
        }
        __syncthreads();
        for (int idv = t; idv < 4096; idv += 512) {
            const int table = idv >> 11;
            const int rem = idv & 2047;
            const int row = rem >> 5;
            const int j   = rem & 31;
            const int qrow = qbase + p * 64 + row;
            const float* rp = (table == 0)
                ? rel_h + (size_t)((qrow >> 5) - j + 31) * HD_
                : rel_w + (size_t)((qrow & 31) - j + 31) * HD_;
            const float* qv = qs + row * 68;
            float acc = 0.f;
            #pragma unroll
            for (int d4 = 0; d4 < 16; ++d4) {
                float4 r4 = *(const float4*)(rp + d4 * 4);
                acc += qv[d4*4+0]*r4.x + qv[d4*4+1]*r4.y + qv[d4*4+2]*r4.z + qv[d4*4+3]*r4.w;
            }
            acc *= LOG2E_;
            if (table == 0) sBH[(p * 64 + row) * 34 + j] = f2b(acc);
            else            sBW[row * 36 + j] = acc;
        }
        __syncthreads();
        if ((wg >> 1) == p) {
            const int qloc = (wg & 1) * 32 + l31;
            #pragma unroll
            for (int m = 0; m < 4; ++m)
                bwv[m] = *(const f32x4*)(sBW + qloc * 36 + m * 8 + hi * 4);
        }
        __syncthreads();
    }

    // ---- staging geometry (r8/r10-verified mapping, per group)
    const int tl = t & 255;
    const int srow = tl >> 2;
    const int sc0  = (tl & 3) * 16;
    const int kvbase = g * 512;
    const u16* kg = kbf + ((size_t)b * HW_ + kvbase + srow) * HD_ + sc0;
    const u16* vg = vtb + (size_t)b * HD_ * HW_ + (size_t)srow * HW_ + kvbase + sc0;
    u16* skw = sK  + srow * 72 + sc0;
    u16* svw = sVt + srow * 72 + sc0;

    // ---- preload tile 0
    s16x8 kr0 = *(const s16x8*)(kg);
    s16x8 kr1 = *(const s16x8*)(kg + 8);
    s16x8 vr0 = *(const s16x8*)(vg);
    s16x8 vr1 = *(const s16x8*)(vg + 8);
    *(s16x8*)(skw)     = kr0;
    *(s16x8*)(skw + 8) = kr1;
    *(s16x8*)(svw)     = vr0;
    *(s16x8*)(svw + 8) = vr1;
    __syncthreads();   // tiles 0 ready

    f32x16 Oacc[2] = {};
    float lsum = 0.f;
    const int bhbase = (qw + l31) * 34 + g * 16;

    for (int kt = 0; kt < 8; ++kt) {
        if (kt < 7) {
            const u16* kn = kg + (size_t)(kt + 1) * 64 * HD_;
            kr0 = *(const s16x8*)(kn);
            kr1 = *(const s16x8*)(kn + 8);
            const u16* vn = vg + (size_t)(kt + 1) * 64;
            vr0 = *(const s16x8*)(vn);
            vr1 = *(const s16x8*)(vn + 8);
        }

        const float bh0 = b2f(sBH[bhbase + 2 * kt]);
        const float bh1 = b2f(sBH[bhbase + 2 * kt + 1]);

        #pragma unroll
        for (int kvt = 0; kvt < 2; ++kvt) {
            f32x16 s = {};
            #pragma unroll
            for (int ck = 0; ck < 4; ++ck) {
                s16x8 kf = *(const s16x8*)(sK + (kvt * 32 + l31) * 72 + ck * 16 + hi * 8);
                s = __builtin_amdgcn_mfma_f32_32x32x16_bf16(kf, qfr[ck], s, 0, 0, 0);
            }
            const float bh = kvt ? bh1 : bh0;

            u32 pw[8];
            #pragma unroll
            for (int m = 0; m < 8; ++m) {
                float p0 = __builtin_amdgcn_exp2f(s[2*m]   + bh + bwv[(2*m)>>2][(2*m)&3]);
                float p1 = __builtin_amdgcn_exp2f(s[2*m+1] + bh + bwv[(2*m+1)>>2][(2*m+1)&3]);
                lsum += p0 + p1;
                pw[m] = (u32)f2b(p0) | ((u32)f2b(p1) << 16);
            }

            #pragma unroll
            for (int cc = 0; cc < 2; ++cc) {
                i32x2 s02 = __builtin_amdgcn_permlane32_swap((int)pw[cc*4+0], (int)pw[cc*4+2], false, false);
                i32x2 s13 = __builtin_amdgcn_permlane32_swap((int)pw[cc*4+1], (int)pw[cc*4+3], false, false);
                u32x4 pau;
                pau.x = (u32)s02.x; pau.y = (u32)s13.x;
                pau.z = (u32)s02.y; pau.w = (u32)s13.y;
                s16x8 pa = *reinterpret_cast<s16x8*>(&pau);
                const int kc = kvt * 2 + cc;
                #pragma unroll
                for (int dt = 0; dt < 2; ++dt) {
                    s16x8 vf = *(const s16x8*)(sVt + (dt * 32 + l31) * 72 + kc * 16 + hi * 8);
                    Oacc[dt] = __builtin_amdgcn_mfma_f32_32x32x16_bf16(pa, vf, Oacc[dt], 0, 0, 0);
                }
            }
        }

        __syncthreads();   // B1: all waves done reading tiles kt
        if (kt < 7) {
            *(s16x8*)(skw)     = kr0;
            *(s16x8*)(skw + 8) = kr1;
            *(s16x8*)(svw)     = vr0;
            *(s16x8*)(svw + 8) = vr1;
        }
        __syncthreads();   // B2: tiles kt+1 visible
    }

    // ---- epilogue: combine the two kv-split halves through LDS
    float lsumF = lsum + __shfl_xor(lsum, 32);   // split-sum for q = qw+l31
    if (g == 1) {
        if (hi == 0) lsumX[qw + l31] = lsumF;
        #pragma unroll
        for (int dt = 0; dt < 2; ++dt) {
            #pragma unroll
            for (int r = 0; r < 16; ++r) {
                const int qloc = (r & 3) + 8 * (r >> 2) + 4 * hi;
                exch[(qw + qloc) * 68 + dt * 32 + l31] = Oacc[dt][r];
            }
        }
    }
    __syncthreads();
    if (g == 0) {
        const float totalF = lsumF + lsumX[qw + l31];
        const int n_img = b / NH_;
        const int head  = b % NH_;
        #pragma unroll
        for (int dt = 0; dt < 2; ++dt) {
            #pragma unroll
            for (int r = 0; r < 16; ++r) {
                const int qloc = (r & 3) + 8 * (r >> 2) + 4 * hi;
                const float linv = 1.0f / __shfl(totalF, qloc);
                const float val = (Oacc[dt][r] + exch[(qw + qloc) * 68 + dt * 32 + l31]) * linv;
                const int qg = qbase + qw + qloc;
                ob[(size_t)(n_img * HW_ + qg) * C_ + head * HD_ + dt * 32 + l31] = f2b(val);
            }
        }
    }
}

extern "C" void kernel_launch(void* const* d_in, const int* in_sizes, int n_in,
                              void* d_out, int out_size, void* d_ws, size_t ws_size,
                              hipStream_t stream) {
    const float* x      = (const float*)d_in[0];
    const float* w_qkv  = (const float*)d_in[1];
    const float* b_qkv  = (const float*)d_in[2];
    const float* w_proj = (const float*)d_in[3];
    const float* b_proj = (const float*)d_in[4];
    const float* rel_h  = (const float*)d_in[5];
    const float* rel_w  = (const float*)d_in[6];
    float* out = (float*)d_out;

    const size_t seg = (size_t)B_ * HW_ * HD_;   // 6,291,456
    char* p = (char*)d_ws;
    u16* xb     = (u16*)p;  p += seg * 2;
    u16* wqkvT  = (u16*)p;  p += (size_t)C3_ * C_ * 2;
    u16* wprojT = (u16*)p;  p += (size_t)C_ * C_ * 2;
    float* qfp  = (float*)p; p += seg * 4;
    u16* kbf    = (u16*)p;  p += seg * 2;
    u16* vtb    = (u16*)p;  p += seg * 2;
    u16* ob     = (u16*)p;  p += seg * 2;

    cvt_bf16<<<2048, 256, 0, stream>>>(x, xb, (int)(seg / 4));
    tcvt_bf16<<<dim3(C3_ / 64, C_ / 64), 256, 0, stream>>>(w_qkv, wqkvT, C_, C3_);
    tcvt_bf16<<<dim3(C_ / 64, C_ / 64), 256, 0, stream>>>(w_proj, wprojT, C_, C_);

    gemm_qkv<<<dim3(C3_ / 128, 8192 / 128), 256, 0, stream>>>(xb, wqkvT, b_qkv, qfp, kbf, vtb);
    attn_mfma<<<768, 512, 45568, stream>>>(qfp, kbf, vtb, rel_h, rel_w, ob);
    gemm_proj<<<dim3(C_ / 128, 8192 / 128), 256, 0, stream>>>(ob, wprojT, b_proj, out);
}

// Round 13
// 322.281 us; speedup vs baseline: 2.0317x; 1.5315x over previous
//
#include <hip/hip_runtime.h>
#include <hip/hip_bf16.h>

#define N_    8
#define H_    32
#define W_    32
#define C_    768
#define NH_   12
#define HD_   64
#define B_    96      // N_*NH_
#define HW_   1024
#define C3_   2304
#define SCALE_ 0.125f
#define LOG2E_ 1.4426950408889634f

typedef __attribute__((ext_vector_type(4))) float f32x4;
typedef __attribute__((ext_vector_type(16))) float f32x16;
typedef __attribute__((ext_vector_type(8))) short s16x8;
typedef __attribute__((ext_vector_type(2))) int i32x2;
typedef __attribute__((ext_vector_type(4))) unsigned int u32x4;
typedef unsigned short u16;
typedef unsigned int u32;

__device__ inline u16 f2b(float x) {
    __hip_bfloat16 h = __float2bfloat16(x);
    return *reinterpret_cast<u16*>(&h);
}
__device__ inline float b2f(u16 x) {
    u32 u = ((u32)x) << 16;
    return *reinterpret_cast<float*>(&u);
}

__device__ __forceinline__ void gld_lds16(const void* g, void* l) {
    __builtin_amdgcn_global_load_lds(
        (const __attribute__((address_space(1))) u32*)g,
        (__attribute__((address_space(3))) u32*)l, 16, 0, 0);
}

// ---------------------------------------------------------------------------
// convert fp32 -> bf16 (vectorized, grid-stride)
// ---------------------------------------------------------------------------
__global__ __launch_bounds__(256) void cvt_bf16(const float* __restrict__ in,
                                                u16* __restrict__ out, int n4) {
    for (int i = blockIdx.x * blockDim.x + threadIdx.x; i < n4; i += gridDim.x * blockDim.x) {
        float4 v = ((const float4*)in)[i];
        ushort4 o;
        o.x = f2b(v.x); o.y = f2b(v.y); o.z = f2b(v.z); o.w = f2b(v.w);
        ((ushort4*)out)[i] = o;
    }
}

// ---------------------------------------------------------------------------
// transpose-convert: in [K][N] fp32 -> out [N][K] bf16, 64x64 tiles
// ---------------------------------------------------------------------------
__global__ __launch_bounds__(256) void tcvt_bf16(const float* __restrict__ in,
                                                 u16* __restrict__ out, int K, int N) {
    __shared__ u16 tile[64][72];
    const int t = threadIdx.x;
    const int k0 = blockIdx.y * 64, n0 = blockIdx.x * 64;
    const int r = t >> 2, c4 = (t & 3) * 16;
    #pragma unroll
    for (int u = 0; u < 4; ++u) {
        float4 v = *(const float4*)(in + (size_t)(k0 + r) * N + n0 + c4 + u * 4);
        tile[c4 + u*4 + 0][r] = f2b(v.x);
        tile[c4 + u*4 + 1][r] = f2b(v.y);
        tile[c4 + u*4 + 2][r] = f2b(v.z);
        tile[c4 + u*4 + 3][r] = f2b(v.w);
    }
    __syncthreads();
    #pragma unroll
    for (int u = 0; u < 2; ++u) {
        s16x8 v;
        #pragma unroll
        for (int e = 0; e < 8; ++e) v[e] = (short)tile[r][c4 + u*8 + e];
        *(s16x8*)(out + (size_t)(n0 + r) * K + k0 + c4 + u*8) = v;
    }
}

// ---------------------------------------------------------------------------
// MFMA GEMM core (m97-style): 128x128 tile, BK=32, 4 waves 2x2, double-buffered
// LDS via global_load_lds width 16, one barrier per K-step. K = 768.
// ---------------------------------------------------------------------------
#define GEMM_CORE(A_, Bt_)                                                           \
    __shared__ u16 sA[2][128 * 32];                                                  \
    __shared__ u16 sB[2][128 * 32];                                                  \
    const int t = threadIdx.x;                                                       \
    const int lane = t & 63;                                                         \
    const int w = t >> 6;                                                            \
    const int wm = w >> 1, wn = w & 1;                                               \
    const int l15 = lane & 15, lg = lane >> 4;                                       \
    const int nbase = blockIdx.x * 128;                                              \
    const int mbase = blockIdx.y * 128;                                              \
    const int srow = lane >> 2;                                                      \
    const int sslot = lane & 3;                                                      \
    const u16* gA0 = (A_) + (size_t)(mbase + w * 16 + srow) * 768 + sslot * 8;       \
    const u16* gA1 = gA0 + (size_t)64 * 768;                                         \
    const u16* gB0 = (Bt_) + (size_t)(nbase + w * 16 + srow) * 768 + sslot * 8;      \
    const u16* gB1 = gB0 + (size_t)64 * 768;                                         \
    f32x4 acc[4][4] = {};                                                            \
    gld_lds16(gA0, &sA[0][w * 512]);                                                 \
    gld_lds16(gA1, &sA[0][(w + 4) * 512]);                                           \
    gld_lds16(gB0, &sB[0][w * 512]);                                                 \
    gld_lds16(gB1, &sB[0][(w + 4) * 512]);                                           \
    for (int kt = 0; kt < 24; ++kt) {                                                \
        const int p = kt & 1;                                                        \
        __syncthreads();                                                             \
        if (kt < 23) {                                                               \
            const int kb = (kt + 1) * 32;                                            \
            gld_lds16(gA0 + kb, &sA[p ^ 1][w * 512]);                                \
            gld_lds16(gA1 + kb, &sA[p ^ 1][(w + 4) * 512]);                          \
            gld_lds16(gB0 + kb, &sB[p ^ 1][w * 512]);                                \
            gld_lds16(gB1 + kb, &sB[p ^ 1][(w + 4) * 512]);                          \
        }                                                                            \
        const u16* pa = &sA[p][(wm * 64 + l15) * 32 + lg * 8];                       \
        const u16* pb = &sB[p][(wn * 64 + l15) * 32 + lg * 8];                       \
        s16x8 afr[4], bfr[4];                                                        \
        _Pragma("unroll")                                                            \
        for (int i = 0; i < 4; ++i) {                                                \
            afr[i] = *(const s16x8*)(pa + i * 512);                                  \
            bfr[i] = *(const s16x8*)(pb + i * 512);                                  \
        }                                                                            \
        _Pragma("unroll")                                                            \
        for (int i = 0; i < 4; ++i)                                                  \
            _Pragma("unroll")                                                        \
            for (int j = 0; j < 4; ++j)                                              \
                acc[i][j] = __builtin_amdgcn_mfma_f32_16x16x32_bf16(afr[i], bfr[j],  \
                                                                    acc[i][j], 0, 0, 0); \
    }

__global__ __launch_bounds__(256) void gemm_qkv(const u16* __restrict__ A,
                                                const u16* __restrict__ Bt,
                                                const float* __restrict__ bias,
                                                float* __restrict__ qout,
                                                u16* __restrict__ kout,
                                                u16* __restrict__ vout) {
    GEMM_CORE(A, Bt)
    const int which = nbase / C_;
    const int head  = ((nbase % C_) >> 6) + wn;
    const int mrow0 = mbase + wm * 64 + lg * 4;
    #pragma unroll
    for (int i = 0; i < 4; ++i) {
        #pragma unroll
        for (int r = 0; r < 4; ++r) {
            const int m = mrow0 + i * 16 + r;
            const size_t bidx = (size_t)((m >> 10) * NH_ + head);
            const int pp = m & 1023;
            #pragma unroll
            for (int j = 0; j < 4; ++j) {
                const int d = j * 16 + l15;
                const float val = acc[i][j][r] + bias[nbase + wn * 64 + d];
                if (which == 0)      qout[(bidx * HW_ + pp) * HD_ + d] = val;
                else if (which == 1) kout[(bidx * HW_ + pp) * HD_ + d] = f2b(val);
                else                 vout[bidx * (size_t)(HW_ * HD_) + (size_t)d * HW_ + pp] = f2b(val);
            }
        }
    }
}

__global__ __launch_bounds__(256) void gemm_proj(const u16* __restrict__ A,
                                                 const u16* __restrict__ Bt,
                                                 const float* __restrict__ bias,
                                                 float* __restrict__ out) {
    GEMM_CORE(A, Bt)
    const int mrow0 = mbase + wm * 64 + lg * 4;
    #pragma unroll
    for (int i = 0; i < 4; ++i) {
        #pragma unroll
        for (int r = 0; r < 4; ++r) {
            const int m = mrow0 + i * 16 + r;
            #pragma unroll
            for (int j = 0; j < 4; ++j) {
                const int n = nbase + wn * 64 + j * 16 + l15;
                out[(size_t)m * C_ + n] = acc[i][j][r] + bias[n];
            }
        }
    }
}

// ---------------------------------------------------------------------------
// Kernel: attn — round-10 datapath + DOUBLE-BUFFERED tiles + ONE raw barrier
// per KV tile with lgkmcnt-only wait (prefetch global loads stay in flight
// across the barrier; they drain at their ds_write use a full compute phase
// after issue).  4 waves x 32 q-rows = 128 q; grid 768 = 96 b x 8 q-tiles.
// 32x32 swapped QK^T, permlane32_swap P redistribution, exp2-folded bias,
// max-free softmax (r10-verified byte-identical math).
// LDS map (bytes):
//   sBH u16[128][34] @0 (8704, persistent)
//   sK0 @8704  sK1 @17920  sVt0 @27136  sVt1 @36352 (each u16[64][72]=9216)
//   qs  f32[64][68] @8704  (prologue transient, overlaps sK0/sK1)
//   sBW f32[64][36] @27136 (prologue transient, overlaps sVt0)
// total 45568 -> 3 blocks/CU (LDS-capped).  No min-waves bound (r11/r12
// lesson: forced occupancy -> VGPR spill; cap ~= 256/arg2).
// ---------------------------------------------------------------------------
__global__ __launch_bounds__(256) void attn_mfma(const float* __restrict__ qf,
                                                 const u16* __restrict__ kbf,
                                                 const u16* __restrict__ vtb,
                                                 const float* __restrict__ rel_h,
                                                 const float* __restrict__ rel_w,
                                                 u16* __restrict__ ob) {
    extern __shared__ char smem[];
    u16*   sBH  = (u16*)smem;                 // [128][34] bf16 (persistent)
    u16*   sK0  = (u16*)(smem + 8704);        // [64][72]
    u16*   sK1  = (u16*)(smem + 17920);       // [64][72]
    u16*   sVt0 = (u16*)(smem + 27136);       // [64][72]
    u16*   sVt1 = (u16*)(smem + 36352);       // [64][72]
    float* qs   = (float*)(smem + 8704);      // [64][68] f32 (prologue only)
    float* sBW  = (float*)(smem + 27136);     // [64][36] f32 (prologue only)

    const int t = threadIdx.x;
    const int lane = t & 63;
    const int w = t >> 6;
    const int l31 = lane & 31;
    const int hi  = lane >> 5;
    const int qw  = w * 32;

    // XCD-bijective swizzle: 768 blocks, 96 per XCD = 12 whole b's
    const int bid = blockIdx.x;
    const int swz = (bid & 7) * 96 + (bid >> 3);
    const int b = swz >> 3;
    const int qbase = (swz & 7) * 128;

    // ---- Q fragments (B-operand of swapped QK^T), pre-scaled by SCALE*log2e
    s16x8 qfr[4];
    {
        const float* qrow = qf + ((size_t)b * HW_ + qbase + qw + l31) * HD_;
        #pragma unroll
        for (int ck = 0; ck < 4; ++ck) {
            float4 x0 = *(const float4*)(qrow + ck * 16 + hi * 8);
            float4 x1 = *(const float4*)(qrow + ck * 16 + hi * 8 + 4);
            qfr[ck][0] = (short)f2b(x0.x * (SCALE_ * LOG2E_));
            qfr[ck][1] = (short)f2b(x0.y * (SCALE_ * LOG2E_));
            qfr[ck][2] = (short)f2b(x0.z * (SCALE_ * LOG2E_));
            qfr[ck][3] = (short)f2b(x0.w * (SCALE_ * LOG2E_));
            qfr[ck][4] = (short)f2b(x1.x * (SCALE_ * LOG2E_));
            qfr[ck][5] = (short)f2b(x1.y * (SCALE_ * LOG2E_));
            qfr[ck][6] = (short)f2b(x1.z * (SCALE_ * LOG2E_));
            qfr[ck][7] = (short)f2b(x1.w * (SCALE_ * LOG2E_));
        }
    }

    // ---- bias tables in two 64-row passes (x log2e); bw hoisted to regs.
    // bwv[m][j] = bw[q][m*8 + 4*hi + j]  (kw(reg r) = (r&3)+8*(r>>2)+4*hi).
    f32x4 bwv[4];
    for (int p = 0; p < 2; ++p) {
        {   // stage qs rows [p*64, p*64+64) (fp32, exact)
            const int row = t >> 2;
            const int c0 = (t & 3) * 16;
            const float* src = qf + ((size_t)b * HW_ + qbase + p * 64 + row) * HD_ + c0;
            #pragma unroll
            for (int u = 0; u < 4; ++u) {
                float4 v4 = *(const float4*)(src + u * 4);
                float* qd = qs + row * 68 + c0 + u * 4;
                qd[0] = v4.x; qd[1] = v4.y; qd[2] = v4.z; qd[3] = v4.w;
            }
        }
        __syncthreads();
        for (int idv = t; idv < 4096; idv += 256) {
            const int table = idv >> 11;
            const int rem = idv & 2047;
            const int row = rem >> 5;
            const int j   = rem & 31;
            const int qrow = qbase + p * 64 + row;
            const float* rp = (table == 0)
                ? rel_h + (size_t)((qrow >> 5) - j + 31) * HD_
                : rel_w + (size_t)((qrow & 31) - j + 31) * HD_;
            const float* qv = qs + row * 68;
            float acc = 0.f;
            #pragma unroll
            for (int d4 = 0; d4 < 16; ++d4) {
                float4 r4 = *(const float4*)(rp + d4 * 4);
                acc += qv[d4*4+0]*r4.x + qv[d4*4+1]*r4.y + qv[d4*4+2]*r4.z + qv[d4*4+3]*r4.w;
            }
            acc *= LOG2E_;
            if (table == 0) sBH[(p * 64 + row) * 34 + j] = f2b(acc);
            else            sBW[row * 36 + j] = acc;
        }
        __syncthreads();
        if ((w >> 1) == p) {
            const int qloc = (w & 1) * 32 + l31;
            #pragma unroll
            for (int m = 0; m < 4; ++m)
                bwv[m] = *(const f32x4*)(sBW + qloc * 36 + m * 8 + hi * 4);
        }
        __syncthreads();
    }

    // ---- staging geometry (r8/r10-verified mapping, pad-72 rows)
    const int srow = t >> 2;
    const int sc0  = (t & 3) * 16;
    const u16* kg = kbf + ((size_t)b * HW_ + srow) * HD_ + sc0;
    const u16* vg = vtb + (size_t)b * HD_ * HW_ + (size_t)srow * HW_ + sc0;
    u16* skw0 = sK0  + srow * 72 + sc0;
    u16* skw1 = sK1  + srow * 72 + sc0;
    u16* svw0 = sVt0 + srow * 72 + sc0;
    u16* svw1 = sVt1 + srow * 72 + sc0;

    // ---- preload tile 0 -> buffer 0
    s16x8 kr0 = *(const s16x8*)(kg);
    s16x8 kr1 = *(const s16x8*)(kg + 8);
    s16x8 vr0 = *(const s16x8*)(vg);
    s16x8 vr1 = *(const s16x8*)(vg + 8);
    *(s16x8*)(skw0)     = kr0;
    *(s16x8*)(skw0 + 8) = kr1;
    *(s16x8*)(svw0)     = vr0;
    *(s16x8*)(svw0 + 8) = vr1;
    __syncthreads();   // buf0 ready

    f32x16 Oacc[2] = {};
    float lsum = 0.f;
    const int bhbase = (qw + l31) * 34;

    auto body = [&](int kt, const u16* sKr, const u16* sVr, u16* skwN, u16* svwN) {
        // issue prefetch for kt+1 (stays in flight across the barrier)
        if (kt < 15) {
            const u16* kn = kg + (size_t)(kt + 1) * 64 * HD_;
            kr0 = *(const s16x8*)(kn);
            kr1 = *(const s16x8*)(kn + 8);
            const u16* vn = vg + (size_t)(kt + 1) * 64;
            vr0 = *(const s16x8*)(vn);
            vr1 = *(const s16x8*)(vn + 8);
        }

        const float bh0 = b2f(sBH[bhbase + 2 * kt]);
        const float bh1 = b2f(sBH[bhbase + 2 * kt + 1]);

        #pragma unroll
        for (int kvt = 0; kvt < 2; ++kvt) {
            f32x16 s = {};
            #pragma unroll
            for (int ck = 0; ck < 4; ++ck) {
                s16x8 kf = *(const s16x8*)(sKr + (kvt * 32 + l31) * 72 + ck * 16 + hi * 8);
                s = __builtin_amdgcn_mfma_f32_32x32x16_bf16(kf, qfr[ck], s, 0, 0, 0);
            }
            const float bh = kvt ? bh1 : bh0;

            u32 pw[8];
            #pragma unroll
            for (int m = 0; m < 8; ++m) {
                float p0 = __builtin_amdgcn_exp2f(s[2*m]   + bh + bwv[(2*m)>>2][(2*m)&3]);
                float p1 = __builtin_amdgcn_exp2f(s[2*m+1] + bh + bwv[(2*m+1)>>2][(2*m+1)&3]);
                lsum += p0 + p1;
                pw[m] = (u32)f2b(p0) | ((u32)f2b(p1) << 16);
            }

            #pragma unroll
            for (int cc = 0; cc < 2; ++cc) {
                i32x2 s02 = __builtin_amdgcn_permlane32_swap((int)pw[cc*4+0], (int)pw[cc*4+2], false, false);
                i32x2 s13 = __builtin_amdgcn_permlane32_swap((int)pw[cc*4+1], (int)pw[cc*4+3], false, false);
                u32x4 pau;
                pau.x = (u32)s02.x; pau.y = (u32)s13.x;
                pau.z = (u32)s02.y; pau.w = (u32)s13.y;
                s16x8 pa = *reinterpret_cast<s16x8*>(&pau);
                const int kc = kvt * 2 + cc;
                #pragma unroll
                for (int dt = 0; dt < 2; ++dt) {
                    s16x8 vf = *(const s16x8*)(sVr + (dt * 32 + l31) * 72 + kc * 16 + hi * 8);
                    Oacc[dt] = __builtin_amdgcn_mfma_f32_32x32x16_bf16(pa, vf, Oacc[dt], 0, 0, 0);
                }
            }
        }

        // write tile kt+1 into the idle buffer (vmcnt wait inserted here by
        // the compiler, covered by the compute phase above)
        if (kt < 15) {
            *(s16x8*)(skwN)     = kr0;
            *(s16x8*)(skwN + 8) = kr1;
            *(s16x8*)(svwN)     = vr0;
            *(s16x8*)(svwN + 8) = vr1;
        }
        // raw barrier: drain LDS ops only; global prefetch stays in flight
        asm volatile("s_waitcnt lgkmcnt(0)" ::: "memory");
        __builtin_amdgcn_s_barrier();
        __builtin_amdgcn_sched_barrier(0);
    };

    for (int k2 = 0; k2 < 8; ++k2) {
        body(2 * k2,     sK0, sVt0, skw1, svw1);
        body(2 * k2 + 1, sK1, sVt1, skw0, svw0);
    }

    // ---- epilogue: lsum holds partials for q = qw + l31 (lane & partner)
    float lsumF = lsum + __shfl_xor(lsum, 32);
    float linv[16];
    #pragma unroll
    for (int r = 0; r < 16; ++r) {
        const int qloc = (r & 3) + 8 * (r >> 2) + 4 * hi;
        linv[r] = 1.0f / __shfl(lsumF, qloc);
    }

    const int n_img = b / NH_;
    const int head  = b % NH_;
    #pragma unroll
    for (int dt = 0; dt < 2; ++dt) {
        #pragma unroll
        for (int r = 0; r < 16; ++r) {
            const int qloc = (r & 3) + 8 * (r >> 2) + 4 * hi;
            const int qg = qbase + qw + qloc;
            ob[(size_t)(n_img * HW_ + qg) * C_ + head * HD_ + dt * 32 + l31] =
                f2b(Oacc[dt][r] * linv[r]);
        }
    }
}

extern "C" void kernel_launch(void* const* d_in, const int* in_sizes, int n_in,
                              void* d_out, int out_size, void* d_ws, size_t ws_size,
                              hipStream_t stream) {
    const float* x      = (const float*)d_in[0];
    const float* w_qkv  = (const float*)d_in[1];
    const float* b_qkv  = (const float*)d_in[2];
    const float* w_proj = (const float*)d_in[3];
    const float* b_proj = (const float*)d_in[4];
    const float* rel_h  = (const float*)d_in[5];
    const float* rel_w  = (const float*)d_in[6];
    float* out = (float*)d_out;

    const size_t seg = (size_t)B_ * HW_ * HD_;   // 6,291,456
    char* p = (char*)d_ws;
    u16* xb     = (u16*)p;  p += seg * 2;
    u16* wqkvT  = (u16*)p;  p += (size_t)C3_ * C_ * 2;
    u16* wprojT = (u16*)p;  p += (size_t)C_ * C_ * 2;
    float* qfp  = (float*)p; p += seg * 4;
    u16* kbf    = (u16*)p;  p += seg * 2;
    u16* vtb    = (u16*)p;  p += seg * 2;
    u16* ob     = (u16*)p;  p += seg * 2;

    cvt_bf16<<<2048, 256, 0, stream>>>(x, xb, (int)(seg / 4));
    tcvt_bf16<<<dim3(C3_ / 64, C_ / 64), 256, 0, stream>>>(w_qkv, wqkvT, C_, C3_);
    tcvt_bf16<<<dim3(C_ / 64, C_ / 64), 256, 0, stream>>>(w_proj, wprojT, C_, C_);

    gemm_qkv<<<dim3(C3_ / 128, 8192 / 128), 256, 0, stream>>>(xb, wqkvT, b_qkv, qfp, kbf, vtb);
    attn_mfma<<<768, 256, 45568, stream>>>(qfp, kbf, vtb, rel_h, rel_w, ob);
    gemm_proj<<<dim3(C_ / 128, 8192 / 128), 256, 0, stream>>>(ob, wprojT, b_proj, out);
}

// Round 14
// 187.459 us; speedup vs baseline: 3.4928x; 1.7192x over previous
//
#include <hip/hip_runtime.h>
#include <hip/hip_bf16.h>

#define N_    8
#define H_    32
#define W_    32
#define C_    768
#define NH_   12
#define HD_   64
#define B_    96      // N_*NH_
#define HW_   1024
#define C3_   2304
#define SCALE_ 0.125f
#define LOG2E_ 1.4426950408889634f

typedef __attribute__((ext_vector_type(4))) float f32x4;
typedef __attribute__((ext_vector_type(16))) float f32x16;
typedef __attribute__((ext_vector_type(8))) short s16x8;
typedef __attribute__((ext_vector_type(2))) int i32x2;
typedef __attribute__((ext_vector_type(2))) unsigned int u32x2;
typedef __attribute__((ext_vector_type(4))) unsigned int u32x4;
typedef unsigned short u16;
typedef unsigned int u32;

__device__ inline u16 f2b(float x) {
    __hip_bfloat16 h = __float2bfloat16(x);
    return *reinterpret_cast<u16*>(&h);
}
__device__ inline float b2f(u16 x) {
    u32 u = ((u32)x) << 16;
    return *reinterpret_cast<float*>(&u);
}

__device__ __forceinline__ void gld_lds16(const void* g, void* l) {
    __builtin_amdgcn_global_load_lds(
        (const __attribute__((address_space(1))) u32*)g,
        (__attribute__((address_space(3))) u32*)l, 16, 0, 0);
}

// ---------------------------------------------------------------------------
// convert fp32 -> bf16 (vectorized, grid-stride)
// ---------------------------------------------------------------------------
__global__ __launch_bounds__(256) void cvt_bf16(const float* __restrict__ in,
                                                u16* __restrict__ out, int n4) {
    for (int i = blockIdx.x * blockDim.x + threadIdx.x; i < n4; i += gridDim.x * blockDim.x) {
        float4 v = ((const float4*)in)[i];
        ushort4 o;
        o.x = f2b(v.x); o.y = f2b(v.y); o.z = f2b(v.z); o.w = f2b(v.w);
        ((ushort4*)out)[i] = o;
    }
}

// ---------------------------------------------------------------------------
// transpose-convert: in [K][N] fp32 -> out [N][K] bf16, 64x64 tiles
// ---------------------------------------------------------------------------
__global__ __launch_bounds__(256) void tcvt_bf16(const float* __restrict__ in,
                                                 u16* __restrict__ out, int K, int N) {
    __shared__ u16 tile[64][72];
    const int t = threadIdx.x;
    const int k0 = blockIdx.y * 64, n0 = blockIdx.x * 64;
    const int r = t >> 2, c4 = (t & 3) * 16;
    #pragma unroll
    for (int u = 0; u < 4; ++u) {
        float4 v = *(const float4*)(in + (size_t)(k0 + r) * N + n0 + c4 + u * 4);
        tile[c4 + u*4 + 0][r] = f2b(v.x);
        tile[c4 + u*4 + 1][r] = f2b(v.y);
        tile[c4 + u*4 + 2][r] = f2b(v.z);
        tile[c4 + u*4 + 3][r] = f2b(v.w);
    }
    __syncthreads();
    #pragma unroll
    for (int u = 0; u < 2; ++u) {
        s16x8 v;
        #pragma unroll
        for (int e = 0; e < 8; ++e) v[e] = (short)tile[r][c4 + u*8 + e];
        *(s16x8*)(out + (size_t)(n0 + r) * K + k0 + c4 + u*8) = v;
    }
}

// ---------------------------------------------------------------------------
// MFMA GEMM core (m97-style): 128x128 tile, BK=32, 4 waves 2x2, double-buffered
// LDS via global_load_lds width 16, one barrier per K-step. K = 768.
// ---------------------------------------------------------------------------
#define GEMM_CORE(A_, Bt_)                                                           \
    __shared__ u16 sA[2][128 * 32];                                                  \
    __shared__ u16 sB[2][128 * 32];                                                  \
    const int t = threadIdx.x;                                                       \
    const int lane = t & 63;                                                         \
    const int w = t >> 6;                                                            \
    const int wm = w >> 1, wn = w & 1;                                               \
    const int l15 = lane & 15, lg = lane >> 4;                                       \
    const int nbase = blockIdx.x * 128;                                              \
    const int mbase = blockIdx.y * 128;                                              \
    const int srow = lane >> 2;                                                      \
    const int sslot = lane & 3;                                                      \
    const u16* gA0 = (A_) + (size_t)(mbase + w * 16 + srow) * 768 + sslot * 8;       \
    const u16* gA1 = gA0 + (size_t)64 * 768;                                         \
    const u16* gB0 = (Bt_) + (size_t)(nbase + w * 16 + srow) * 768 + sslot * 8;      \
    const u16* gB1 = gB0 + (size_t)64 * 768;                                         \
    f32x4 acc[4][4] = {};                                                            \
    gld_lds16(gA0, &sA[0][w * 512]);                                                 \
    gld_lds16(gA1, &sA[0][(w + 4) * 512]);                                           \
    gld_lds16(gB0, &sB[0][w * 512]);                                                 \
    gld_lds16(gB1, &sB[0][(w + 4) * 512]);                                           \
    for (int kt = 0; kt < 24; ++kt) {                                                \
        const int p = kt & 1;                                                        \
        __syncthreads();                                                             \
        if (kt < 23) {                                                               \
            const int kb = (kt + 1) * 32;                                            \
            gld_lds16(gA0 + kb, &sA[p ^ 1][w * 512]);                                \
            gld_lds16(gA1 + kb, &sA[p ^ 1][(w + 4) * 512]);                          \
            gld_lds16(gB0 + kb, &sB[p ^ 1][w * 512]);                                \
            gld_lds16(gB1 + kb, &sB[p ^ 1][(w + 4) * 512]);                          \
        }                                                                            \
        const u16* pa = &sA[p][(wm * 64 + l15) * 32 + lg * 8];                       \
        const u16* pb = &sB[p][(wn * 64 + l15) * 32 + lg * 8];                       \
        s16x8 afr[4], bfr[4];                                                        \
        _Pragma("unroll")                                                            \
        for (int i = 0; i < 4; ++i) {                                                \
            afr[i] = *(const s16x8*)(pa + i * 512);                                  \
            bfr[i] = *(const s16x8*)(pb + i * 512);                                  \
        }                                                                            \
        _Pragma("unroll")                                                            \
        for (int i = 0; i < 4; ++i)                                                  \
            _Pragma("unroll")                                                        \
            for (int j = 0; j < 4; ++j)                                              \
                acc[i][j] = __builtin_amdgcn_mfma_f32_16x16x32_bf16(afr[i], bfr[j],  \
                                                                    acc[i][j], 0, 0, 0); \
    }

__global__ __launch_bounds__(256) void gemm_qkv(const u16* __restrict__ A,
                                                const u16* __restrict__ Bt,
                                                const float* __restrict__ bias,
                                                float* __restrict__ qout,
                                                u16* __restrict__ kout,
                                                u16* __restrict__ vout) {
    GEMM_CORE(A, Bt)
    const int which = nbase / C_;
    const int head  = ((nbase % C_) >> 6) + wn;
    const int mrow0 = mbase + wm * 64 + lg * 4;
    #pragma unroll
    for (int i = 0; i < 4; ++i) {
        #pragma unroll
        for (int r = 0; r < 4; ++r) {
            const int m = mrow0 + i * 16 + r;
            const size_t bidx = (size_t)((m >> 10) * NH_ + head);
            const int pp = m & 1023;
            #pragma unroll
            for (int j = 0; j < 4; ++j) {
                const int d = j * 16 + l15;
                const float val = acc[i][j][r] + bias[nbase + wn * 64 + d];
                if (which == 0)      qout[(bidx * HW_ + pp) * HD_ + d] = val;
                else if (which == 1) kout[(bidx * HW_ + pp) * HD_ + d] = f2b(val);
                else                 vout[bidx * (size_t)(HW_ * HD_) + (size_t)d * HW_ + pp] = f2b(val);
            }
        }
    }
}

__global__ __launch_bounds__(256) void gemm_proj(const u16* __restrict__ A,
                                                 const u16* __restrict__ Bt,
                                                 const float* __restrict__ bias,
                                                 float* __restrict__ out) {
    GEMM_CORE(A, Bt)
    const int mrow0 = mbase + wm * 64 + lg * 4;
    #pragma unroll
    for (int i = 0; i < 4; ++i) {
        #pragma unroll
        for (int r = 0; r < 4; ++r) {
            const int m = mrow0 + i * 16 + r;
            #pragma unroll
            for (int j = 0; j < 4; ++j) {
                const int n = nbase + wn * 64 + j * 16 + l15;
                out[(size_t)m * C_ + n] = acc[i][j][r] + bias[n];
            }
        }
    }
}

// ---------------------------------------------------------------------------
// ef_gemm: F = Q @ rel_h^T, E = Q @ rel_w^T (x LOG2E), bf16 out [98304][64]
// (63 valid cols, col 63 garbage/unused).  Then:
//   bias_h[q][kh] = F[q][(q>>5)+31-kh],  bias_w[q][kw] = E[q][(q&31)+31-kw].
// Block: 256 thr / 4 waves; wave = 32 q rows; grid 768.  Per wave:
// 2 tables x 2 delta-halves x 4 ck MFMAs (swapped: lane's col = its own q).
// ---------------------------------------------------------------------------
__global__ __launch_bounds__(256) void ef_gemm(const float* __restrict__ qf,
                                               const float* __restrict__ rel_h,
                                               const float* __restrict__ rel_w,
                                               u16* __restrict__ Fg,
                                               u16* __restrict__ Eg) {
    const int t = threadIdx.x;
    const int lane = t & 63;
    const int w = t >> 6;
    const int l31 = lane & 31;
    const int hi  = lane >> 5;
    const size_t Mrow = (size_t)blockIdx.x * 128 + w * 32 + l31;

    // Q B-fragment: lane holds Q[q=Mrow][d = ck*16 + hi*8 + j]
    s16x8 qb[4];
    {
        const float* qrow = qf + Mrow * HD_;
        #pragma unroll
        for (int ck = 0; ck < 4; ++ck) {
            float4 x0 = *(const float4*)(qrow + ck * 16 + hi * 8);
            float4 x1 = *(const float4*)(qrow + ck * 16 + hi * 8 + 4);
            qb[ck][0] = (short)f2b(x0.x); qb[ck][1] = (short)f2b(x0.y);
            qb[ck][2] = (short)f2b(x0.z); qb[ck][3] = (short)f2b(x0.w);
            qb[ck][4] = (short)f2b(x1.x); qb[ck][5] = (short)f2b(x1.y);
            qb[ck][6] = (short)f2b(x1.z); qb[ck][7] = (short)f2b(x1.w);
        }
    }

    #pragma unroll
    for (int tb = 0; tb < 2; ++tb) {
        const float* R = tb ? rel_w : rel_h;
        u16* og = (tb ? Eg : Fg) + Mrow * 64;
        #pragma unroll
        for (int hh = 0; hh < 2; ++hh) {
            const int dr = hh * 32 + l31;
            const float* rrow = R + (size_t)(dr > 62 ? 62 : dr) * HD_;  // clamp pad row
            f32x16 acc = {};
            #pragma unroll
            for (int ck = 0; ck < 4; ++ck) {
                float4 r0 = *(const float4*)(rrow + ck * 16 + hi * 8);
                float4 r1 = *(const float4*)(rrow + ck * 16 + hi * 8 + 4);
                s16x8 af;
                af[0] = (short)f2b(r0.x * LOG2E_); af[1] = (short)f2b(r0.y * LOG2E_);
                af[2] = (short)f2b(r0.z * LOG2E_); af[3] = (short)f2b(r0.w * LOG2E_);
                af[4] = (short)f2b(r1.x * LOG2E_); af[5] = (short)f2b(r1.y * LOG2E_);
                af[6] = (short)f2b(r1.z * LOG2E_); af[7] = (short)f2b(r1.w * LOG2E_);
                acc = __builtin_amdgcn_mfma_f32_32x32x16_bf16(af, qb[ck], acc, 0, 0, 0);
            }
            // D row (delta) for reg r: (r&3) + 8*(r>>2) + 4*hi; regs 4u..4u+3 consecutive
            #pragma unroll
            for (int u = 0; u < 4; ++u) {
                u32x2 pkd;
                pkd.x = (u32)f2b(acc[4*u+0]) | ((u32)f2b(acc[4*u+1]) << 16);
                pkd.y = (u32)f2b(acc[4*u+2]) | ((u32)f2b(acc[4*u+3]) << 16);
                *(u32x2*)(og + hh * 32 + u * 8 + 4 * hi) = pkd;
            }
        }
    }
}

// ---------------------------------------------------------------------------
// Kernel: attn — round-13 main loop (dbuf, one raw barrier/tile, lgkmcnt-only
// wait) with the bias PROLOGUE REPLACED by reads of precomputed E/F tables
// (ef_gemm).  + T5 s_setprio around MFMA clusters.
// LDS map (bytes): sBH u16[128][34] @0 (8704); sK0 @8704 sK1 @17920
//   sVt0 @27136 sVt1 @36352 (each u16[64][72]) -> total 45568, 3 blocks/CU.
// ---------------------------------------------------------------------------
__global__ __launch_bounds__(256) void attn_mfma(const float* __restrict__ qf,
                                                 const u16* __restrict__ kbf,
                                                 const u16* __restrict__ vtb,
                                                 const u16* __restrict__ Fg,
                                                 const u16* __restrict__ Eg,
                                                 u16* __restrict__ ob) {
    extern __shared__ char smem[];
    u16*   sBH  = (u16*)smem;                 // [128][34] bf16 (persistent)
    u16*   sK0  = (u16*)(smem + 8704);
    u16*   sK1  = (u16*)(smem + 17920);
    u16*   sVt0 = (u16*)(smem + 27136);
    u16*   sVt1 = (u16*)(smem + 36352);

    const int t = threadIdx.x;
    const int lane = t & 63;
    const int w = t >> 6;
    const int l31 = lane & 31;
    const int hi  = lane >> 5;
    const int qw  = w * 32;

    // XCD-bijective swizzle: 768 blocks, 96 per XCD = 12 whole b's
    const int bid = blockIdx.x;
    const int swz = (bid & 7) * 96 + (bid >> 3);
    const int b = swz >> 3;
    const int qbase = (swz & 7) * 128;

    // ---- Q fragments (B-operand of swapped QK^T), pre-scaled by SCALE*log2e
    s16x8 qfr[4];
    {
        const float* qrow = qf + ((size_t)b * HW_ + qbase + qw + l31) * HD_;
        #pragma unroll
        for (int ck = 0; ck < 4; ++ck) {
            float4 x0 = *(const float4*)(qrow + ck * 16 + hi * 8);
            float4 x1 = *(const float4*)(qrow + ck * 16 + hi * 8 + 4);
            qfr[ck][0] = (short)f2b(x0.x * (SCALE_ * LOG2E_));
            qfr[ck][1] = (short)f2b(x0.y * (SCALE_ * LOG2E_));
            qfr[ck][2] = (short)f2b(x0.z * (SCALE_ * LOG2E_));
            qfr[ck][3] = (short)f2b(x0.w * (SCALE_ * LOG2E_));
            qfr[ck][4] = (short)f2b(x1.x * (SCALE_ * LOG2E_));
            qfr[ck][5] = (short)f2b(x1.y * (SCALE_ * LOG2E_));
            qfr[ck][6] = (short)f2b(x1.z * (SCALE_ * LOG2E_));
            qfr[ck][7] = (short)f2b(x1.w * (SCALE_ * LOG2E_));
        }
    }

    // ---- sBH fill: bias_h[q][kh] = F[q][(q>>5)+31-kh]  (reversed at copy)
    {
        const u16* Fb = Fg + (size_t)b * HW_ * 64;
        for (int idv = t; idv < 4096; idv += 256) {
            const int row = idv >> 5;
            const int kh  = idv & 31;
            const int qg  = qbase + row;
            sBH[row * 34 + kh] = Fb[(size_t)qg * 64 + (qg >> 5) + 31 - kh];
        }
    }

    // ---- bwv regs: bias_w[q][kw] = E[q][(q&31)+31-kw], kw = m*8+4*hi+j
    f32x4 bwv[4];
    {
        const int qmy = qbase + qw + l31;                 // q&31 == l31
        const u16* Erow = Eg + (size_t)(b * HW_ + qmy) * 64;
        #pragma unroll
        for (int m = 0; m < 4; ++m)
            #pragma unroll
            for (int j = 0; j < 4; ++j)
                bwv[m][j] = b2f(Erow[l31 + 31 - (m * 8 + 4 * hi + j)]);
    }

    // ---- staging geometry (r8/r10-verified mapping, pad-72 rows)
    const int srow = t >> 2;
    const int sc0  = (t & 3) * 16;
    const u16* kg = kbf + ((size_t)b * HW_ + srow) * HD_ + sc0;
    const u16* vg = vtb + (size_t)b * HD_ * HW_ + (size_t)srow * HW_ + sc0;
    u16* skw0 = sK0  + srow * 72 + sc0;
    u16* skw1 = sK1  + srow * 72 + sc0;
    u16* svw0 = sVt0 + srow * 72 + sc0;
    u16* svw1 = sVt1 + srow * 72 + sc0;

    // ---- preload tile 0 -> buffer 0
    s16x8 kr0 = *(const s16x8*)(kg);
    s16x8 kr1 = *(const s16x8*)(kg + 8);
    s16x8 vr0 = *(const s16x8*)(vg);
    s16x8 vr1 = *(const s16x8*)(vg + 8);
    *(s16x8*)(skw0)     = kr0;
    *(s16x8*)(skw0 + 8) = kr1;
    *(s16x8*)(svw0)     = vr0;
    *(s16x8*)(svw0 + 8) = vr1;
    __syncthreads();   // sBH + buf0 visible

    f32x16 Oacc[2] = {};
    float lsum = 0.f;
    const int bhbase = (qw + l31) * 34;

    auto body = [&](int kt, const u16* sKr, const u16* sVr, u16* skwN, u16* svwN) {
        if (kt < 15) {
            const u16* kn = kg + (size_t)(kt + 1) * 64 * HD_;
            kr0 = *(const s16x8*)(kn);
            kr1 = *(const s16x8*)(kn + 8);
            const u16* vn = vg + (size_t)(kt + 1) * 64;
            vr0 = *(const s16x8*)(vn);
            vr1 = *(const s16x8*)(vn + 8);
        }

        const float bh0 = b2f(sBH[bhbase + 2 * kt]);
        const float bh1 = b2f(sBH[bhbase + 2 * kt + 1]);

        #pragma unroll
        for (int kvt = 0; kvt < 2; ++kvt) {
            f32x16 s = {};
            __builtin_amdgcn_s_setprio(1);
            #pragma unroll
            for (int ck = 0; ck < 4; ++ck) {
                s16x8 kf = *(const s16x8*)(sKr + (kvt * 32 + l31) * 72 + ck * 16 + hi * 8);
                s = __builtin_amdgcn_mfma_f32_32x32x16_bf16(kf, qfr[ck], s, 0, 0, 0);
            }
            __builtin_amdgcn_s_setprio(0);
            const float bh = kvt ? bh1 : bh0;

            u32 pw[8];
            #pragma unroll
            for (int m = 0; m < 8; ++m) {
                float p0 = __builtin_amdgcn_exp2f(s[2*m]   + bh + bwv[(2*m)>>2][(2*m)&3]);
                float p1 = __builtin_amdgcn_exp2f(s[2*m+1] + bh + bwv[(2*m+1)>>2][(2*m+1)&3]);
                lsum += p0 + p1;
                pw[m] = (u32)f2b(p0) | ((u32)f2b(p1) << 16);
            }

            __builtin_amdgcn_s_setprio(1);
            #pragma unroll
            for (int cc = 0; cc < 2; ++cc) {
                i32x2 s02 = __builtin_amdgcn_permlane32_swap((int)pw[cc*4+0], (int)pw[cc*4+2], false, false);
                i32x2 s13 = __builtin_amdgcn_permlane32_swap((int)pw[cc*4+1], (int)pw[cc*4+3], false, false);
                u32x4 pau;
                pau.x = (u32)s02.x; pau.y = (u32)s13.x;
                pau.z = (u32)s02.y; pau.w = (u32)s13.y;
                s16x8 pa = *reinterpret_cast<s16x8*>(&pau);
                const int kc = kvt * 2 + cc;
                #pragma unroll
                for (int dt = 0; dt < 2; ++dt) {
                    s16x8 vf = *(const s16x8*)(sVr + (dt * 32 + l31) * 72 + kc * 16 + hi * 8);
                    Oacc[dt] = __builtin_amdgcn_mfma_f32_32x32x16_bf16(pa, vf, Oacc[dt], 0, 0, 0);
                }
            }
            __builtin_amdgcn_s_setprio(0);
        }

        if (kt < 15) {
            *(s16x8*)(skwN)     = kr0;
            *(s16x8*)(skwN + 8) = kr1;
            *(s16x8*)(svwN)     = vr0;
            *(s16x8*)(svwN + 8) = vr1;
        }
        asm volatile("s_waitcnt lgkmcnt(0)" ::: "memory");
        __builtin_amdgcn_s_barrier();
        __builtin_amdgcn_sched_barrier(0);
    };

    for (int k2 = 0; k2 < 8; ++k2) {
        body(2 * k2,     sK0, sVt0, skw1, svw1);
        body(2 * k2 + 1, sK1, sVt1, skw0, svw0);
    }

    // ---- epilogue
    float lsumF = lsum + __shfl_xor(lsum, 32);
    float linv[16];
    #pragma unroll
    for (int r = 0; r < 16; ++r) {
        const int qloc = (r & 3) + 8 * (r >> 2) + 4 * hi;
        linv[r] = 1.0f / __shfl(lsumF, qloc);
    }

    const int n_img = b / NH_;
    const int head  = b % NH_;
    #pragma unroll
    for (int dt = 0; dt < 2; ++dt) {
        #pragma unroll
        for (int r = 0; r < 16; ++r) {
            const int qloc = (r & 3) + 8 * (r >> 2) + 4 * hi;
            const int qg = qbase + qw + qloc;
            ob[(size_t)(n_img * HW_ + qg) * C_ + head * HD_ + dt * 32 + l31] =
                f2b(Oacc[dt][r] * linv[r]);
        }
    }
}

extern "C" void kernel_launch(void* const* d_in, const int* in_sizes, int n_in,
                              void* d_out, int out_size, void* d_ws, size_t ws_size,
                              hipStream_t stream) {
    const float* x      = (const float*)d_in[0];
    const float* w_qkv  = (const float*)d_in[1];
    const float* b_qkv  = (const float*)d_in[2];
    const float* w_proj = (const float*)d_in[3];
    const float* b_proj = (const float*)d_in[4];
    const float* rel_h  = (const float*)d_in[5];
    const float* rel_w  = (const float*)d_in[6];
    float* out = (float*)d_out;

    const size_t seg = (size_t)B_ * HW_ * HD_;   // 6,291,456
    char* p = (char*)d_ws;
    u16* xb     = (u16*)p;  p += seg * 2;
    u16* wqkvT  = (u16*)p;  p += (size_t)C3_ * C_ * 2;
    u16* wprojT = (u16*)p;  p += (size_t)C_ * C_ * 2;
    float* qfp  = (float*)p; p += seg * 4;
    u16* kbf    = (u16*)p;  p += seg * 2;
    u16* vtb    = (u16*)p;  p += seg * 2;
    u16* ob     = (u16*)p;  p += seg * 2;
    u16* Fg     = (u16*)p;  p += seg * 2;        // [98304][64] bf16
    u16* Eg     = (u16*)p;  p += seg * 2;        // [98304][64] bf16

    cvt_bf16<<<2048, 256, 0, stream>>>(x, xb, (int)(seg / 4));
    tcvt_bf16<<<dim3(C3_ / 64, C_ / 64), 256, 0, stream>>>(w_qkv, wqkvT, C_, C3_);
    tcvt_bf16<<<dim3(C_ / 64, C_ / 64), 256, 0, stream>>>(w_proj, wprojT, C_, C_);

    gemm_qkv<<<dim3(C3_ / 128, 8192 / 128), 256, 0, stream>>>(xb, wqkvT, b_qkv, qfp, kbf, vtb);
    ef_gemm<<<768, 256, 0, stream>>>(qfp, rel_h, rel_w, Fg, Eg);
    attn_mfma<<<768, 256, 45568, stream>>>(qfp, kbf, vtb, Fg, Eg, ob);
    gemm_proj<<<dim3(C_ / 128, 8192 / 128), 256, 0, stream>>>(ob, wprojT, b_proj, out);
}

// Round 15
// 160.359 us; speedup vs baseline: 4.0831x; 1.1690x over previous
//
#include <hip/hip_runtime.h>
#include <hip/hip_bf16.h>

#define N_    8
#define H_    32
#define W_    32
#define C_    768
#define NH_   12
#define HD_   64
#define B_    96      // N_*NH_
#define HW_   1024
#define C3_   2304
#define SCALE_ 0.125f
#define LOG2E_ 1.4426950408889634f

typedef __attribute__((ext_vector_type(4))) float f32x4;
typedef __attribute__((ext_vector_type(16))) float f32x16;
typedef __attribute__((ext_vector_type(8))) short s16x8;
typedef __attribute__((ext_vector_type(2))) int i32x2;
typedef __attribute__((ext_vector_type(2))) unsigned int u32x2;
typedef __attribute__((ext_vector_type(4))) unsigned int u32x4;
typedef unsigned short u16;
typedef unsigned int u32;

__device__ inline u16 f2b(float x) {
    __hip_bfloat16 h = __float2bfloat16(x);
    return *reinterpret_cast<u16*>(&h);
}
__device__ inline float b2f(u16 x) {
    u32 u = ((u32)x) << 16;
    return *reinterpret_cast<float*>(&u);
}

__device__ __forceinline__ void gld_lds16(const void* g, void* l) {
    __builtin_amdgcn_global_load_lds(
        (const __attribute__((address_space(1))) u32*)g,
        (__attribute__((address_space(3))) u32*)l, 16, 0, 0);
}

// ---------------------------------------------------------------------------
// convert fp32 -> bf16 (vectorized, grid-stride)
// ---------------------------------------------------------------------------
__global__ __launch_bounds__(256) void cvt_bf16(const float* __restrict__ in,
                                                u16* __restrict__ out, int n4) {
    for (int i = blockIdx.x * blockDim.x + threadIdx.x; i < n4; i += gridDim.x * blockDim.x) {
        float4 v = ((const float4*)in)[i];
        ushort4 o;
        o.x = f2b(v.x); o.y = f2b(v.y); o.z = f2b(v.z); o.w = f2b(v.w);
        ((ushort4*)out)[i] = o;
    }
}

// ---------------------------------------------------------------------------
// transpose-convert: in [K][N] fp32 -> out [N][K] bf16, 64x64 tiles
// ---------------------------------------------------------------------------
__global__ __launch_bounds__(256) void tcvt_bf16(const float* __restrict__ in,
                                                 u16* __restrict__ out, int K, int N) {
    __shared__ u16 tile[64][72];
    const int t = threadIdx.x;
    const int k0 = blockIdx.y * 64, n0 = blockIdx.x * 64;
    const int r = t >> 2, c4 = (t & 3) * 16;
    #pragma unroll
    for (int u = 0; u < 4; ++u) {
        float4 v = *(const float4*)(in + (size_t)(k0 + r) * N + n0 + c4 + u * 4);
        tile[c4 + u*4 + 0][r] = f2b(v.x);
        tile[c4 + u*4 + 1][r] = f2b(v.y);
        tile[c4 + u*4 + 2][r] = f2b(v.z);
        tile[c4 + u*4 + 3][r] = f2b(v.w);
    }
    __syncthreads();
    #pragma unroll
    for (int u = 0; u < 2; ++u) {
        s16x8 v;
        #pragma unroll
        for (int e = 0; e < 8; ++e) v[e] = (short)tile[r][c4 + u*8 + e];
        *(s16x8*)(out + (size_t)(n0 + r) * K + k0 + c4 + u*8) = v;
    }
}

// ---------------------------------------------------------------------------
// gemm_qkv: 128x128 tile, BK=32, 4 waves 2x2, double-buffered global_load_lds
// (m97 structure, r3-verified main loop) + NEW coalesced epilogue:
// outputs repacked through LDS tile T[128][136] u16 (pitch 272 B: transposed
// writes land 2-way bank-free, row reads 16B-aligned), then stored as
// 128/256-byte coalesced segments.  q is now BF16 (consumers round to bf16
// anyway).  v transposed in LDS, not via global scatter.
// Dynamic LDS 34816 B: main loop uses [0,32768) as sA/sB; epilogue reuses
// [0,34816) as T (barrier-separated).
// ---------------------------------------------------------------------------
__global__ __launch_bounds__(256) void gemm_qkv(const u16* __restrict__ A,
                                                const u16* __restrict__ Bt,
                                                const float* __restrict__ bias,
                                                u16* __restrict__ qout,
                                                u16* __restrict__ kout,
                                                u16* __restrict__ vout) {
    extern __shared__ char smem[];
    u16* sA = (u16*)smem;                    // 2 x [128*32] u16
    u16* sB = (u16*)(smem + 16384);          // 2 x [128*32] u16
    u16* T  = (u16*)smem;                    // [128][136] u16 (epilogue)

    const int t = threadIdx.x;
    const int lane = t & 63;
    const int w = t >> 6;
    const int wm = w >> 1, wn = w & 1;
    const int l15 = lane & 15, lg = lane >> 4;
    const int nbase = blockIdx.x * 128;
    const int mbase = blockIdx.y * 128;
    const int srow = lane >> 2;
    const int sslot = lane & 3;
    const u16* gA0 = A + (size_t)(mbase + w * 16 + srow) * 768 + sslot * 8;
    const u16* gA1 = gA0 + (size_t)64 * 768;
    const u16* gB0 = Bt + (size_t)(nbase + w * 16 + srow) * 768 + sslot * 8;
    const u16* gB1 = gB0 + (size_t)64 * 768;
    f32x4 acc[4][4] = {};
    gld_lds16(gA0, sA + w * 512);
    gld_lds16(gA1, sA + (w + 4) * 512);
    gld_lds16(gB0, sB + w * 512);
    gld_lds16(gB1, sB + (w + 4) * 512);
    for (int kt = 0; kt < 24; ++kt) {
        const int p = kt & 1;
        __syncthreads();
        if (kt < 23) {
            const int kb = (kt + 1) * 32;
            gld_lds16(gA0 + kb, sA + (p ^ 1) * 4096 + w * 512);
            gld_lds16(gA1 + kb, sA + (p ^ 1) * 4096 + (w + 4) * 512);
            gld_lds16(gB0 + kb, sB + (p ^ 1) * 4096 + w * 512);
            gld_lds16(gB1 + kb, sB + (p ^ 1) * 4096 + (w + 4) * 512);
        }
        const u16* pa = sA + p * 4096 + (wm * 64 + l15) * 32 + lg * 8;
        const u16* pb = sB + p * 4096 + (wn * 64 + l15) * 32 + lg * 8;
        s16x8 afr[4], bfr[4];
        #pragma unroll
        for (int i = 0; i < 4; ++i) {
            afr[i] = *(const s16x8*)(pa + i * 512);
            bfr[i] = *(const s16x8*)(pb + i * 512);
        }
        #pragma unroll
        for (int i = 0; i < 4; ++i)
            #pragma unroll
            for (int j = 0; j < 4; ++j)
                acc[i][j] = __builtin_amdgcn_mfma_f32_16x16x32_bf16(afr[i], bfr[j],
                                                                    acc[i][j], 0, 0, 0);
    }

    // ---- epilogue: LDS repack + coalesced stores
    const int which = nbase / C_;
    const int head0 = (nbase % C_) >> 6;
    const int n_img = mbase >> 10;
    const int pbase = mbase & 1023;
    __syncthreads();   // main-loop LDS reads done; T may overwrite sA/sB

    if (which < 2) {
        // row-major: T[lm][lc]
        #pragma unroll
        for (int i = 0; i < 4; ++i)
            #pragma unroll
            for (int r = 0; r < 4; ++r) {
                const int lm = wm * 64 + i * 16 + lg * 4 + r;
                #pragma unroll
                for (int j = 0; j < 4; ++j) {
                    const int lc = wn * 64 + j * 16 + l15;
                    T[lm * 136 + lc] = f2b(acc[i][j][r] + bias[nbase + lc]);
                }
            }
    } else {
        // transposed: T[lc][lm]  (lane-consecutive lc -> 272B stride -> 2-way free)
        #pragma unroll
        for (int i = 0; i < 4; ++i)
            #pragma unroll
            for (int r = 0; r < 4; ++r) {
                const int lm = wm * 64 + i * 16 + lg * 4 + r;
                #pragma unroll
                for (int j = 0; j < 4; ++j) {
                    const int lc = wn * 64 + j * 16 + l15;
                    T[lc * 136 + lm] = f2b(acc[i][j][r] + bias[nbase + lc]);
                }
            }
    }
    __syncthreads();

    if (which < 2) {
        u16* dst = (which == 0) ? qout : kout;
        #pragma unroll
        for (int pass = 0; pass < 4; ++pass) {
            const int lm = pass * 32 + (t >> 3);
            #pragma unroll
            for (int hh = 0; hh < 2; ++hh) {
                s16x8 row = *(const s16x8*)(T + lm * 136 + hh * 64 + (t & 7) * 8);
                const size_t bidx = (size_t)(n_img * NH_ + head0 + hh);
                *(s16x8*)(dst + (bidx * HW_ + pbase + lm) * HD_ + (t & 7) * 8) = row;
            }
        }
    } else {
        #pragma unroll
        for (int pass = 0; pass < 8; ++pass) {
            const int lc = pass * 16 + (t >> 4);
            s16x8 row = *(const s16x8*)(T + lc * 136 + (t & 15) * 8);
            const int hh = lc >> 6, d = lc & 63;
            const size_t bidx = (size_t)(n_img * NH_ + head0 + hh);
            *(s16x8*)(vout + bidx * (size_t)(HW_ * HD_) + (size_t)d * HW_ + pbase + (t & 15) * 8) = row;
        }
    }
}

// ---------------------------------------------------------------------------
// MFMA GEMM core (m97-style) — used by gemm_proj only.
// ---------------------------------------------------------------------------
#define GEMM_CORE(A_, Bt_)                                                           \
    __shared__ u16 sA[2][128 * 32];                                                  \
    __shared__ u16 sB[2][128 * 32];                                                  \
    const int t = threadIdx.x;                                                       \
    const int lane = t & 63;                                                         \
    const int w = t >> 6;                                                            \
    const int wm = w >> 1, wn = w & 1;                                               \
    const int l15 = lane & 15, lg = lane >> 4;                                       \
    const int nbase = blockIdx.x * 128;                                              \
    const int mbase = blockIdx.y * 128;                                              \
    const int srow = lane >> 2;                                                      \
    const int sslot = lane & 3;                                                      \
    const u16* gA0 = (A_) + (size_t)(mbase + w * 16 + srow) * 768 + sslot * 8;       \
    const u16* gA1 = gA0 + (size_t)64 * 768;                                         \
    const u16* gB0 = (Bt_) + (size_t)(nbase + w * 16 + srow) * 768 + sslot * 8;      \
    const u16* gB1 = gB0 + (size_t)64 * 768;                                         \
    f32x4 acc[4][4] = {};                                                            \
    gld_lds16(gA0, &sA[0][w * 512]);                                                 \
    gld_lds16(gA1, &sA[0][(w + 4) * 512]);                                           \
    gld_lds16(gB0, &sB[0][w * 512]);                                                 \
    gld_lds16(gB1, &sB[0][(w + 4) * 512]);                                           \
    for (int kt = 0; kt < 24; ++kt) {                                                \
        const int p = kt & 1;                                                        \
        __syncthreads();                                                             \
        if (kt < 23) {                                                               \
            const int kb = (kt + 1) * 32;                                            \
            gld_lds16(gA0 + kb, &sA[p ^ 1][w * 512]);                                \
            gld_lds16(gA1 + kb, &sA[p ^ 1][(w + 4) * 512]);                          \
            gld_lds16(gB0 + kb, &sB[p ^ 1][w * 512]);                                \
            gld_lds16(gB1 + kb, &sB[p ^ 1][(w + 4) * 512]);                          \
        }                                                                            \
        const u16* pa = &sA[p][(wm * 64 + l15) * 32 + lg * 8];                       \
        const u16* pb = &sB[p][(wn * 64 + l15) * 32 + lg * 8];                       \
        s16x8 afr[4], bfr[4];                                                        \
        _Pragma("unroll")                                                            \
        for (int i = 0; i < 4; ++i) {                                                \
            afr[i] = *(const s16x8*)(pa + i * 512);                                  \
            bfr[i] = *(const s16x8*)(pb + i * 512);                                  \
        }                                                                            \
        _Pragma("unroll")                                                            \
        for (int i = 0; i < 4; ++i)                                                  \
            _Pragma("unroll")                                                        \
            for (int j = 0; j < 4; ++j)                                              \
                acc[i][j] = __builtin_amdgcn_mfma_f32_16x16x32_bf16(afr[i], bfr[j],  \
                                                                    acc[i][j], 0, 0, 0); \
    }

__global__ __launch_bounds__(256) void gemm_proj(const u16* __restrict__ A,
                                                 const u16* __restrict__ Bt,
                                                 const float* __restrict__ bias,
                                                 float* __restrict__ out) {
    GEMM_CORE(A, Bt)
    const int mrow0 = mbase + wm * 64 + lg * 4;
    #pragma unroll
    for (int i = 0; i < 4; ++i) {
        #pragma unroll
        for (int r = 0; r < 4; ++r) {
            const int m = mrow0 + i * 16 + r;
            #pragma unroll
            for (int j = 0; j < 4; ++j) {
                const int n = nbase + wn * 64 + j * 16 + l15;
                out[(size_t)m * C_ + n] = acc[i][j][r] + bias[n];
            }
        }
    }
}

// ---------------------------------------------------------------------------
// ef_gemm: F = Q @ rel_h^T, E = Q @ rel_w^T (x LOG2E), bf16 out [98304][64].
//   bias_h[q][kh] = F[q][(q>>5)+31-kh],  bias_w[q][kw] = E[q][(q&31)+31-kw].
// Q now read as bf16 directly.
// ---------------------------------------------------------------------------
__global__ __launch_bounds__(256) void ef_gemm(const u16* __restrict__ qb_,
                                               const float* __restrict__ rel_h,
                                               const float* __restrict__ rel_w,
                                               u16* __restrict__ Fg,
                                               u16* __restrict__ Eg) {
    const int t = threadIdx.x;
    const int lane = t & 63;
    const int w = t >> 6;
    const int l31 = lane & 31;
    const int hi  = lane >> 5;
    const size_t Mrow = (size_t)blockIdx.x * 128 + w * 32 + l31;

    s16x8 qb[4];
    {
        const u16* qrow = qb_ + Mrow * HD_;
        #pragma unroll
        for (int ck = 0; ck < 4; ++ck)
            qb[ck] = *(const s16x8*)(qrow + ck * 16 + hi * 8);
    }

    #pragma unroll
    for (int tb = 0; tb < 2; ++tb) {
        const float* R = tb ? rel_w : rel_h;
        u16* og = (tb ? Eg : Fg) + Mrow * 64;
        #pragma unroll
        for (int hh = 0; hh < 2; ++hh) {
            const int dr = hh * 32 + l31;
            const float* rrow = R + (size_t)(dr > 62 ? 62 : dr) * HD_;
            f32x16 acc = {};
            #pragma unroll
            for (int ck = 0; ck < 4; ++ck) {
                float4 r0 = *(const float4*)(rrow + ck * 16 + hi * 8);
                float4 r1 = *(const float4*)(rrow + ck * 16 + hi * 8 + 4);
                s16x8 af;
                af[0] = (short)f2b(r0.x * LOG2E_); af[1] = (short)f2b(r0.y * LOG2E_);
                af[2] = (short)f2b(r0.z * LOG2E_); af[3] = (short)f2b(r0.w * LOG2E_);
                af[4] = (short)f2b(r1.x * LOG2E_); af[5] = (short)f2b(r1.y * LOG2E_);
                af[6] = (short)f2b(r1.z * LOG2E_); af[7] = (short)f2b(r1.w * LOG2E_);
                acc = __builtin_amdgcn_mfma_f32_32x32x16_bf16(af, qb[ck], acc, 0, 0, 0);
            }
            #pragma unroll
            for (int u = 0; u < 4; ++u) {
                u32x2 pkd;
                pkd.x = (u32)f2b(acc[4*u+0]) | ((u32)f2b(acc[4*u+1]) << 16);
                pkd.y = (u32)f2b(acc[4*u+2]) | ((u32)f2b(acc[4*u+3]) << 16);
                *(u32x2*)(og + hh * 32 + u * 8 + 4 * hi) = pkd;
            }
        }
    }
}

// ---------------------------------------------------------------------------
// Kernel: attn — r13 main loop (dbuf, one raw barrier/tile, lgkmcnt-only
// wait) + precomputed E/F bias tables (ef_gemm) + T5 setprio.
// Q read as bf16.  LDS map: sBH u16[128][34] @0; sK0 @8704 sK1 @17920
//   sVt0 @27136 sVt1 @36352 -> 45568 B, 3 blocks/CU.
// ---------------------------------------------------------------------------
__global__ __launch_bounds__(256) void attn_mfma(const u16* __restrict__ qb_,
                                                 const u16* __restrict__ kbf,
                                                 const u16* __restrict__ vtb,
                                                 const u16* __restrict__ Fg,
                                                 const u16* __restrict__ Eg,
                                                 u16* __restrict__ ob) {
    extern __shared__ char smem[];
    u16*   sBH  = (u16*)smem;                 // [128][34] bf16 (persistent)
    u16*   sK0  = (u16*)(smem + 8704);
    u16*   sK1  = (u16*)(smem + 17920);
    u16*   sVt0 = (u16*)(smem + 27136);
    u16*   sVt1 = (u16*)(smem + 36352);

    const int t = threadIdx.x;
    const int lane = t & 63;
    const int w = t >> 6;
    const int l31 = lane & 31;
    const int hi  = lane >> 5;
    const int qw  = w * 32;

    // XCD-bijective swizzle: 768 blocks, 96 per XCD = 12 whole b's
    const int bid = blockIdx.x;
    const int swz = (bid & 7) * 96 + (bid >> 3);
    const int b = swz >> 3;
    const int qbase = (swz & 7) * 128;

    // ---- Q fragments (B-operand of swapped QK^T), bf16 src, scaled
    s16x8 qfr[4];
    {
        const u16* qrow = qb_ + ((size_t)b * HW_ + qbase + qw + l31) * HD_;
        #pragma unroll
        for (int ck = 0; ck < 4; ++ck) {
            s16x8 qv = *(const s16x8*)(qrow + ck * 16 + hi * 8);
            #pragma unroll
            for (int e = 0; e < 8; ++e)
                qfr[ck][e] = (short)f2b(b2f((u16)qv[e]) * (SCALE_ * LOG2E_));
        }
    }

    // ---- sBH fill: bias_h[q][kh] = F[q][(q>>5)+31-kh]
    {
        const u16* Fb = Fg + (size_t)b * HW_ * 64;
        for (int idv = t; idv < 4096; idv += 256) {
            const int row = idv >> 5;
            const int kh  = idv & 31;
            const int qg  = qbase + row;
            sBH[row * 34 + kh] = Fb[(size_t)qg * 64 + (qg >> 5) + 31 - kh];
        }
    }

    // ---- bwv regs: bias_w[q][kw] = E[q][(q&31)+31-kw], kw = m*8+4*hi+j
    f32x4 bwv[4];
    {
        const int qmy = qbase + qw + l31;
        const u16* Erow = Eg + (size_t)(b * HW_ + qmy) * 64;
        #pragma unroll
        for (int m = 0; m < 4; ++m)
            #pragma unroll
            for (int j = 0; j < 4; ++j)
                bwv[m][j] = b2f(Erow[l31 + 31 - (m * 8 + 4 * hi + j)]);
    }

    // ---- staging geometry (r8/r10-verified mapping, pad-72 rows)
    const int srow = t >> 2;
    const int sc0  = (t & 3) * 16;
    const u16* kg = kbf + ((size_t)b * HW_ + srow) * HD_ + sc0;
    const u16* vg = vtb + (size_t)b * HD_ * HW_ + (size_t)srow * HW_ + sc0;
    u16* skw0 = sK0  + srow * 72 + sc0;
    u16* skw1 = sK1  + srow * 72 + sc0;
    u16* svw0 = sVt0 + srow * 72 + sc0;
    u16* svw1 = sVt1 + srow * 72 + sc0;

    // ---- preload tile 0 -> buffer 0
    s16x8 kr0 = *(const s16x8*)(kg);
    s16x8 kr1 = *(const s16x8*)(kg + 8);
    s16x8 vr0 = *(const s16x8*)(vg);
    s16x8 vr1 = *(const s16x8*)(vg + 8);
    *(s16x8*)(skw0)     = kr0;
    *(s16x8*)(skw0 + 8) = kr1;
    *(s16x8*)(svw0)     = vr0;
    *(s16x8*)(svw0 + 8) = vr1;
    __syncthreads();   // sBH + buf0 visible

    f32x16 Oacc[2] = {};
    float lsum = 0.f;
    const int bhbase = (qw + l31) * 34;

    auto body = [&](int kt, const u16* sKr, const u16* sVr, u16* skwN, u16* svwN) {
        if (kt < 15) {
            const u16* kn = kg + (size_t)(kt + 1) * 64 * HD_;
            kr0 = *(const s16x8*)(kn);
            kr1 = *(const s16x8*)(kn + 8);
            const u16* vn = vg + (size_t)(kt + 1) * 64;
            vr0 = *(const s16x8*)(vn);
            vr1 = *(const s16x8*)(vn + 8);
        }

        const float bh0 = b2f(sBH[bhbase + 2 * kt]);
        const float bh1 = b2f(sBH[bhbase + 2 * kt + 1]);

        #pragma unroll
        for (int kvt = 0; kvt < 2; ++kvt) {
            f32x16 s = {};
            __builtin_amdgcn_s_setprio(1);
            #pragma unroll
            for (int ck = 0; ck < 4; ++ck) {
                s16x8 kf = *(const s16x8*)(sKr + (kvt * 32 + l31) * 72 + ck * 16 + hi * 8);
                s = __builtin_amdgcn_mfma_f32_32x32x16_bf16(kf, qfr[ck], s, 0, 0, 0);
            }
            __builtin_amdgcn_s_setprio(0);
            const float bh = kvt ? bh1 : bh0;

            u32 pw[8];
            #pragma unroll
            for (int m = 0; m < 8; ++m) {
                float p0 = __builtin_amdgcn_exp2f(s[2*m]   + bh + bwv[(2*m)>>2][(2*m)&3]);
                float p1 = __builtin_amdgcn_exp2f(s[2*m+1] + bh + bwv[(2*m+1)>>2][(2*m+1)&3]);
                lsum += p0 + p1;
                pw[m] = (u32)f2b(p0) | ((u32)f2b(p1) << 16);
            }

            __builtin_amdgcn_s_setprio(1);
            #pragma unroll
            for (int cc = 0; cc < 2; ++cc) {
                i32x2 s02 = __builtin_amdgcn_permlane32_swap((int)pw[cc*4+0], (int)pw[cc*4+2], false, false);
                i32x2 s13 = __builtin_amdgcn_permlane32_swap((int)pw[cc*4+1], (int)pw[cc*4+3], false, false);
                u32x4 pau;
                pau.x = (u32)s02.x; pau.y = (u32)s13.x;
                pau.z = (u32)s02.y; pau.w = (u32)s13.y;
                s16x8 pa = *reinterpret_cast<s16x8*>(&pau);
                const int kc = kvt * 2 + cc;
                #pragma unroll
                for (int dt = 0; dt < 2; ++dt) {
                    s16x8 vf = *(const s16x8*)(sVr + (dt * 32 + l31) * 72 + kc * 16 + hi * 8);
                    Oacc[dt] = __builtin_amdgcn_mfma_f32_32x32x16_bf16(pa, vf, Oacc[dt], 0, 0, 0);
                }
            }
            __builtin_amdgcn_s_setprio(0);
        }

        if (kt < 15) {
            *(s16x8*)(skwN)     = kr0;
            *(s16x8*)(skwN + 8) = kr1;
            *(s16x8*)(svwN)     = vr0;
            *(s16x8*)(svwN + 8) = vr1;
        }
        asm volatile("s_waitcnt lgkmcnt(0)" ::: "memory");
        __builtin_amdgcn_s_barrier();
        __builtin_amdgcn_sched_barrier(0);
    };

    for (int k2 = 0; k2 < 8; ++k2) {
        body(2 * k2,     sK0, sVt0, skw1, svw1);
        body(2 * k2 + 1, sK1, sVt1, skw0, svw0);
    }

    // ---- epilogue
    float lsumF = lsum + __shfl_xor(lsum, 32);
    float linv[16];
    #pragma unroll
    for (int r = 0; r < 16; ++r) {
        const int qloc = (r & 3) + 8 * (r >> 2) + 4 * hi;
        linv[r] = 1.0f / __shfl(lsumF, qloc);
    }

    const int n_img = b / NH_;
    const int head  = b % NH_;
    #pragma unroll
    for (int dt = 0; dt < 2; ++dt) {
        #pragma unroll
        for (int r = 0; r < 16; ++r) {
            const int qloc = (r & 3) + 8 * (r >> 2) + 4 * hi;
            const int qg = qbase + qw + qloc;
            ob[(size_t)(n_img * HW_ + qg) * C_ + head * HD_ + dt * 32 + l31] =
                f2b(Oacc[dt][r] * linv[r]);
        }
    }
}

extern "C" void kernel_launch(void* const* d_in, const int* in_sizes, int n_in,
                              void* d_out, int out_size, void* d_ws, size_t ws_size,
                              hipStream_t stream) {
    const float* x      = (const float*)d_in[0];
    const float* w_qkv  = (const float*)d_in[1];
    const float* b_qkv  = (const float*)d_in[2];
    const float* w_proj = (const float*)d_in[3];
    const float* b_proj = (const float*)d_in[4];
    const float* rel_h  = (const float*)d_in[5];
    const float* rel_w  = (const float*)d_in[6];
    float* out = (float*)d_out;

    const size_t seg = (size_t)B_ * HW_ * HD_;   // 6,291,456
    char* p = (char*)d_ws;
    u16* xb     = (u16*)p;  p += seg * 2;
    u16* wqkvT  = (u16*)p;  p += (size_t)C3_ * C_ * 2;
    u16* wprojT = (u16*)p;  p += (size_t)C_ * C_ * 2;
    u16* qb     = (u16*)p;  p += seg * 2;        // bf16 now
    u16* kbf    = (u16*)p;  p += seg * 2;
    u16* vtb    = (u16*)p;  p += seg * 2;
    u16* ob     = (u16*)p;  p += seg * 2;
    u16* Fg     = (u16*)p;  p += seg * 2;        // [98304][64] bf16
    u16* Eg     = (u16*)p;  p += seg * 2;        // [98304][64] bf16

    cvt_bf16<<<2048, 256, 0, stream>>>(x, xb, (int)(seg / 4));
    tcvt_bf16<<<dim3(C3_ / 64, C_ / 64), 256, 0, stream>>>(w_qkv, wqkvT, C_, C3_);
    tcvt_bf16<<<dim3(C_ / 64, C_ / 64), 256, 0, stream>>>(w_proj, wprojT, C_, C_);

    gemm_qkv<<<dim3(C3_ / 128, 8192 / 128), 256, 34816, stream>>>(xb, wqkvT, b_qkv, qb, kbf, vtb);
    ef_gemm<<<768, 256, 0, stream>>>(qb, rel_h, rel_w, Fg, Eg);
    attn_mfma<<<768, 256, 45568, stream>>>(qb, kbf, vtb, Fg, Eg, ob);
    gemm_proj<<<dim3(C_ / 128, 8192 / 128), 256, 0, stream>>>(ob, wprojT, b_proj, out);
}

// Round 16
// 142.796 us; speedup vs baseline: 4.5853x; 1.1230x over previous
//
#include <hip/hip_runtime.h>
#include <hip/hip_bf16.h>

#define N_    8
#define H_    32
#define W_    32
#define C_    768
#define NH_   12
#define HD_   64
#define B_    96      // N_*NH_
#define HW_   1024
#define C3_   2304
#define SCALE_ 0.125f
#define LOG2E_ 1.4426950408889634f

typedef __attribute__((ext_vector_type(4))) float f32x4;
typedef __attribute__((ext_vector_type(16))) float f32x16;
typedef __attribute__((ext_vector_type(8))) short s16x8;
typedef __attribute__((ext_vector_type(2))) int i32x2;
typedef __attribute__((ext_vector_type(2))) unsigned int u32x2;
typedef __attribute__((ext_vector_type(4))) unsigned int u32x4;
typedef unsigned short u16;
typedef unsigned int u32;

__device__ inline u16 f2b(float x) {
    __hip_bfloat16 h = __float2bfloat16(x);
    return *reinterpret_cast<u16*>(&h);
}
__device__ inline float b2f(u16 x) {
    u32 u = ((u32)x) << 16;
    return *reinterpret_cast<float*>(&u);
}

__device__ __forceinline__ void gld_lds16(const void* g, void* l) {
    __builtin_amdgcn_global_load_lds(
        (const __attribute__((address_space(1))) u32*)g,
        (__attribute__((address_space(3))) u32*)l, 16, 0, 0);
}

// ---------------------------------------------------------------------------
// convert fp32 -> bf16 (vectorized, grid-stride)
// ---------------------------------------------------------------------------
__global__ __launch_bounds__(256) void cvt_bf16(const float* __restrict__ in,
                                                u16* __restrict__ out, int n4) {
    for (int i = blockIdx.x * blockDim.x + threadIdx.x; i < n4; i += gridDim.x * blockDim.x) {
        float4 v = ((const float4*)in)[i];
        ushort4 o;
        o.x = f2b(v.x); o.y = f2b(v.y); o.z = f2b(v.z); o.w = f2b(v.w);
        ((ushort4*)out)[i] = o;
    }
}

// ---------------------------------------------------------------------------
// transpose-convert: in [K][N] fp32 -> out [N][K] bf16, 64x64 tiles
// ---------------------------------------------------------------------------
__global__ __launch_bounds__(256) void tcvt_bf16(const float* __restrict__ in,
                                                 u16* __restrict__ out, int K, int N) {
    __shared__ u16 tile[64][72];
    const int t = threadIdx.x;
    const int k0 = blockIdx.y * 64, n0 = blockIdx.x * 64;
    const int r = t >> 2, c4 = (t & 3) * 16;
    #pragma unroll
    for (int u = 0; u < 4; ++u) {
        float4 v = *(const float4*)(in + (size_t)(k0 + r) * N + n0 + c4 + u * 4);
        tile[c4 + u*4 + 0][r] = f2b(v.x);
        tile[c4 + u*4 + 1][r] = f2b(v.y);
        tile[c4 + u*4 + 2][r] = f2b(v.z);
        tile[c4 + u*4 + 3][r] = f2b(v.w);
    }
    __syncthreads();
    #pragma unroll
    for (int u = 0; u < 2; ++u) {
        s16x8 v;
        #pragma unroll
        for (int e = 0; e < 8; ++e) v[e] = (short)tile[r][c4 + u*8 + e];
        *(s16x8*)(out + (size_t)(n0 + r) * K + k0 + c4 + u*8) = v;
    }
}

// ---------------------------------------------------------------------------
// GEMM core, 3-DEEP pipeline (T3/T4-lite): 128x128 tile, BK=32, 4 waves 2x2.
// Loads for tile kt+2 issued at iter kt; barrier waits s_waitcnt vmcnt(4)
// (oldest 4 loads = tile kt+1 resident; tile kt+2's 4 stay IN FLIGHT across
// the barrier).  Each wave waits its own loads -> all-wave residency holds.
// Raw s_barrier + lgkmcnt(0) (ds_read drain only) + sched_barrier(0).
// XCD-bijective block swizzle (grid%8==0): per-XCD contiguous m-panels ->
// A/B L2-resident.  Dynamic LDS: 3x(8KB A + 8KB B) = 49152 B.
// K = 768 fixed (24 steps).  NT_ = N/128 tile count.
// ---------------------------------------------------------------------------
#define G3_ISSUE(KB, BUF)                                                            \
    gld_lds16(gA0 + (KB), sAb + (BUF) * 4096 + w * 512);                             \
    gld_lds16(gA1 + (KB), sAb + (BUF) * 4096 + (w + 4) * 512);                       \
    gld_lds16(gB0 + (KB), sBb + (BUF) * 4096 + w * 512);                             \
    gld_lds16(gB1 + (KB), sBb + (BUF) * 4096 + (w + 4) * 512);

#define G3_COMP(BUF)                                                                 \
    {                                                                                \
        const u16* pa = sAb + (BUF) * 4096 + (wm * 64 + l15) * 32 + lg * 8;          \
        const u16* pb = sBb + (BUF) * 4096 + (wn * 64 + l15) * 32 + lg * 8;          \
        s16x8 afr[4], bfr[4];                                                        \
        _Pragma("unroll")                                                            \
        for (int i = 0; i < 4; ++i) {                                                \
            afr[i] = *(const s16x8*)(pa + i * 512);                                  \
            bfr[i] = *(const s16x8*)(pb + i * 512);                                  \
        }                                                                            \
        _Pragma("unroll")                                                            \
        for (int i = 0; i < 4; ++i)                                                  \
            _Pragma("unroll")                                                        \
            for (int j = 0; j < 4; ++j)                                              \
                acc[i][j] = __builtin_amdgcn_mfma_f32_16x16x32_bf16(afr[i], bfr[j],  \
                                                                    acc[i][j], 0, 0, 0); \
    }

#define G3_BAR4                                                                      \
    asm volatile("s_waitcnt vmcnt(4) lgkmcnt(0)" ::: "memory");                      \
    __builtin_amdgcn_s_barrier();                                                    \
    __builtin_amdgcn_sched_barrier(0);

#define G3_BAR0                                                                      \
    asm volatile("s_waitcnt vmcnt(0) lgkmcnt(0)" ::: "memory");                      \
    __builtin_amdgcn_s_barrier();                                                    \
    __builtin_amdgcn_sched_barrier(0);

#define GEMM_CORE3(A_, Bt_, NT_)                                                     \
    extern __shared__ char smem[];                                                   \
    u16* sAb = (u16*)smem;                   /* 3 x [128*32] u16 */                  \
    u16* sBb = (u16*)(smem + 24576);         /* 3 x [128*32] u16 */                  \
    const int t = threadIdx.x;                                                       \
    const int lane = t & 63;                                                         \
    const int w = t >> 6;                                                            \
    const int wm = w >> 1, wn = w & 1;                                               \
    const int l15 = lane & 15, lg = lane >> 4;                                       \
    const int per = (int)gridDim.x >> 3;                                             \
    const int swz = ((int)blockIdx.x & 7) * per + ((int)blockIdx.x >> 3);            \
    const int nbase = (swz % (NT_)) * 128;                                           \
    const int mbase = (swz / (NT_)) * 128;                                           \
    const int srow = lane >> 2;                                                      \
    const int sslot = lane & 3;                                                      \
    const u16* gA0 = (A_) + (size_t)(mbase + w * 16 + srow) * 768 + sslot * 8;       \
    const u16* gA1 = gA0 + (size_t)64 * 768;                                         \
    const u16* gB0 = (Bt_) + (size_t)(nbase + w * 16 + srow) * 768 + sslot * 8;      \
    const u16* gB1 = gB0 + (size_t)64 * 768;                                         \
    f32x4 acc[4][4] = {};                                                            \
    G3_ISSUE(0, 0)                                                                   \
    G3_ISSUE(32, 1)                                                                  \
    G3_BAR4          /* tile 0 resident; tile 1 in flight */                         \
    for (int k3 = 0; k3 < 7; ++k3) {                                                 \
        const int kb = k3 * 96;                                                      \
        G3_ISSUE(kb + 64, 2)  G3_COMP(0)  G3_BAR4                                    \
        G3_ISSUE(kb + 96, 0)  G3_COMP(1)  G3_BAR4                                    \
        G3_ISSUE(kb + 128, 1) G3_COMP(2)  G3_BAR4                                    \
    }                                                                                \
    G3_ISSUE(736, 2) G3_COMP(0) G3_BAR4   /* kt=21: issue t23 */                     \
    G3_COMP(1) G3_BAR0                    /* kt=22: drain t23 */                     \
    G3_COMP(2) G3_BAR0                    /* kt=23 */

// qkv = x @ w_qkv + b_qkv; outputs bf16 q/k [b][p][64], v transposed
// [b][64][p]; coalesced epilogue through LDS tile T[128][136].
__global__ __launch_bounds__(256) void gemm_qkv(const u16* __restrict__ A,
                                                const u16* __restrict__ Bt,
                                                const float* __restrict__ bias,
                                                u16* __restrict__ qout,
                                                u16* __restrict__ kout,
                                                u16* __restrict__ vout) {
    GEMM_CORE3(A, Bt, 18)
    u16* T = (u16*)smem;                    // [128][136] (reuses pipeline LDS)

    const int which = nbase / C_;
    const int head0 = (nbase % C_) >> 6;
    const int n_img = mbase >> 10;
    const int pbase = mbase & 1023;
    // final G3_BAR0 above guarantees all waves' ds_reads complete

    if (which < 2) {
        #pragma unroll
        for (int i = 0; i < 4; ++i)
            #pragma unroll
            for (int r = 0; r < 4; ++r) {
                const int lm = wm * 64 + i * 16 + lg * 4 + r;
                #pragma unroll
                for (int j = 0; j < 4; ++j) {
                    const int lc = wn * 64 + j * 16 + l15;
                    T[lm * 136 + lc] = f2b(acc[i][j][r] + bias[nbase + lc]);
                }
            }
    } else {
        #pragma unroll
        for (int i = 0; i < 4; ++i)
            #pragma unroll
            for (int r = 0; r < 4; ++r) {
                const int lm = wm * 64 + i * 16 + lg * 4 + r;
                #pragma unroll
                for (int j = 0; j < 4; ++j) {
                    const int lc = wn * 64 + j * 16 + l15;
                    T[lc * 136 + lm] = f2b(acc[i][j][r] + bias[nbase + lc]);
                }
            }
    }
    __syncthreads();

    if (which < 2) {
        u16* dst = (which == 0) ? qout : kout;
        #pragma unroll
        for (int pass = 0; pass < 4; ++pass) {
            const int lm = pass * 32 + (t >> 3);
            #pragma unroll
            for (int hh = 0; hh < 2; ++hh) {
                s16x8 row = *(const s16x8*)(T + lm * 136 + hh * 64 + (t & 7) * 8);
                const size_t bidx = (size_t)(n_img * NH_ + head0 + hh);
                *(s16x8*)(dst + (bidx * HW_ + pbase + lm) * HD_ + (t & 7) * 8) = row;
            }
        }
    } else {
        #pragma unroll
        for (int pass = 0; pass < 8; ++pass) {
            const int lc = pass * 16 + (t >> 4);
            s16x8 row = *(const s16x8*)(T + lc * 136 + (t & 15) * 8);
            const int hh = lc >> 6, d = lc & 63;
            const size_t bidx = (size_t)(n_img * NH_ + head0 + hh);
            *(s16x8*)(vout + bidx * (size_t)(HW_ * HD_) + (size_t)d * HW_ + pbase + (t & 15) * 8) = row;
        }
    }
}

// out = o @ w_proj + b_proj, fp32 out
__global__ __launch_bounds__(256) void gemm_proj(const u16* __restrict__ A,
                                                 const u16* __restrict__ Bt,
                                                 const float* __restrict__ bias,
                                                 float* __restrict__ out) {
    GEMM_CORE3(A, Bt, 6)
    const int mrow0 = mbase + wm * 64 + lg * 4;
    #pragma unroll
    for (int i = 0; i < 4; ++i) {
        #pragma unroll
        for (int r = 0; r < 4; ++r) {
            const int m = mrow0 + i * 16 + r;
            #pragma unroll
            for (int j = 0; j < 4; ++j) {
                const int n = nbase + wn * 64 + j * 16 + l15;
                out[(size_t)m * C_ + n] = acc[i][j][r] + bias[n];
            }
        }
    }
}

// ---------------------------------------------------------------------------
// ef_gemm: F = Q @ rel_h^T, E = Q @ rel_w^T (x LOG2E), bf16 out [98304][64].
//   bias_h[q][kh] = F[q][(q>>5)+31-kh],  bias_w[q][kw] = E[q][(q&31)+31-kw].
// ---------------------------------------------------------------------------
__global__ __launch_bounds__(256) void ef_gemm(const u16* __restrict__ qb_,
                                               const float* __restrict__ rel_h,
                                               const float* __restrict__ rel_w,
                                               u16* __restrict__ Fg,
                                               u16* __restrict__ Eg) {
    const int t = threadIdx.x;
    const int lane = t & 63;
    const int w = t >> 6;
    const int l31 = lane & 31;
    const int hi  = lane >> 5;
    const size_t Mrow = (size_t)blockIdx.x * 128 + w * 32 + l31;

    s16x8 qb[4];
    {
        const u16* qrow = qb_ + Mrow * HD_;
        #pragma unroll
        for (int ck = 0; ck < 4; ++ck)
            qb[ck] = *(const s16x8*)(qrow + ck * 16 + hi * 8);
    }

    #pragma unroll
    for (int tb = 0; tb < 2; ++tb) {
        const float* R = tb ? rel_w : rel_h;
        u16* og = (tb ? Eg : Fg) + Mrow * 64;
        #pragma unroll
        for (int hh = 0; hh < 2; ++hh) {
            const int dr = hh * 32 + l31;
            const float* rrow = R + (size_t)(dr > 62 ? 62 : dr) * HD_;
            f32x16 acc = {};
            #pragma unroll
            for (int ck = 0; ck < 4; ++ck) {
                float4 r0 = *(const float4*)(rrow + ck * 16 + hi * 8);
                float4 r1 = *(const float4*)(rrow + ck * 16 + hi * 8 + 4);
                s16x8 af;
                af[0] = (short)f2b(r0.x * LOG2E_); af[1] = (short)f2b(r0.y * LOG2E_);
                af[2] = (short)f2b(r0.z * LOG2E_); af[3] = (short)f2b(r0.w * LOG2E_);
                af[4] = (short)f2b(r1.x * LOG2E_); af[5] = (short)f2b(r1.y * LOG2E_);
                af[6] = (short)f2b(r1.z * LOG2E_); af[7] = (short)f2b(r1.w * LOG2E_);
                acc = __builtin_amdgcn_mfma_f32_32x32x16_bf16(af, qb[ck], acc, 0, 0, 0);
            }
            #pragma unroll
            for (int u = 0; u < 4; ++u) {
                u32x2 pkd;
                pkd.x = (u32)f2b(acc[4*u+0]) | ((u32)f2b(acc[4*u+1]) << 16);
                pkd.y = (u32)f2b(acc[4*u+2]) | ((u32)f2b(acc[4*u+3]) << 16);
                *(u32x2*)(og + hh * 32 + u * 8 + 4 * hi) = pkd;
            }
        }
    }
}

// ---------------------------------------------------------------------------
// attn — r13 main loop (dbuf, one raw barrier/tile, lgkmcnt-only wait) +
// precomputed E/F bias tables + T5 setprio.  (unchanged from round 15)
// LDS: sBH u16[128][34] @0; sK0 @8704 sK1 @17920 sVt0 @27136 sVt1 @36352
// -> 45568 B, 3 blocks/CU.
// ---------------------------------------------------------------------------
__global__ __launch_bounds__(256) void attn_mfma(const u16* __restrict__ qb_,
                                                 const u16* __restrict__ kbf,
                                                 const u16* __restrict__ vtb,
                                                 const u16* __restrict__ Fg,
                                                 const u16* __restrict__ Eg,
                                                 u16* __restrict__ ob) {
    extern __shared__ char smem[];
    u16*   sBH  = (u16*)smem;
    u16*   sK0  = (u16*)(smem + 8704);
    u16*   sK1  = (u16*)(smem + 17920);
    u16*   sVt0 = (u16*)(smem + 27136);
    u16*   sVt1 = (u16*)(smem + 36352);

    const int t = threadIdx.x;
    const int lane = t & 63;
    const int w = t >> 6;
    const int l31 = lane & 31;
    const int hi  = lane >> 5;
    const int qw  = w * 32;

    const int bid = blockIdx.x;
    const int swz = (bid & 7) * 96 + (bid >> 3);
    const int b = swz >> 3;
    const int qbase = (swz & 7) * 128;

    s16x8 qfr[4];
    {
        const u16* qrow = qb_ + ((size_t)b * HW_ + qbase + qw + l31) * HD_;
        #pragma unroll
        for (int ck = 0; ck < 4; ++ck) {
            s16x8 qv = *(const s16x8*)(qrow + ck * 16 + hi * 8);
            #pragma unroll
            for (int e = 0; e < 8; ++e)
                qfr[ck][e] = (short)f2b(b2f((u16)qv[e]) * (SCALE_ * LOG2E_));
        }
    }

    {
        const u16* Fb = Fg + (size_t)b * HW_ * 64;
        for (int idv = t; idv < 4096; idv += 256) {
            const int row = idv >> 5;
            const int kh  = idv & 31;
            const int qg  = qbase + row;
            sBH[row * 34 + kh] = Fb[(size_t)qg * 64 + (qg >> 5) + 31 - kh];
        }
    }

    f32x4 bwv[4];
    {
        const int qmy = qbase + qw + l31;
        const u16* Erow = Eg + (size_t)(b * HW_ + qmy) * 64;
        #pragma unroll
        for (int m = 0; m < 4; ++m)
            #pragma unroll
            for (int j = 0; j < 4; ++j)
                bwv[m][j] = b2f(Erow[l31 + 31 - (m * 8 + 4 * hi + j)]);
    }

    const int srow = t >> 2;
    const int sc0  = (t & 3) * 16;
    const u16* kg = kbf + ((size_t)b * HW_ + srow) * HD_ + sc0;
    const u16* vg = vtb + (size_t)b * HD_ * HW_ + (size_t)srow * HW_ + sc0;
    u16* skw0 = sK0  + srow * 72 + sc0;
    u16* skw1 = sK1  + srow * 72 + sc0;
    u16* svw0 = sVt0 + srow * 72 + sc0;
    u16* svw1 = sVt1 + srow * 72 + sc0;

    s16x8 kr0 = *(const s16x8*)(kg);
    s16x8 kr1 = *(const s16x8*)(kg + 8);
    s16x8 vr0 = *(const s16x8*)(vg);
    s16x8 vr1 = *(const s16x8*)(vg + 8);
    *(s16x8*)(skw0)     = kr0;
    *(s16x8*)(skw0 + 8) = kr1;
    *(s16x8*)(svw0)     = vr0;
    *(s16x8*)(svw0 + 8) = vr1;
    __syncthreads();

    f32x16 Oacc[2] = {};
    float lsum = 0.f;
    const int bhbase = (qw + l31) * 34;

    auto body = [&](int kt, const u16* sKr, const u16* sVr, u16* skwN, u16* svwN) {
        if (kt < 15) {
            const u16* kn = kg + (size_t)(kt + 1) * 64 * HD_;
            kr0 = *(const s16x8*)(kn);
            kr1 = *(const s16x8*)(kn + 8);
            const u16* vn = vg + (size_t)(kt + 1) * 64;
            vr0 = *(const s16x8*)(vn);
            vr1 = *(const s16x8*)(vn + 8);
        }

        const float bh0 = b2f(sBH[bhbase + 2 * kt]);
        const float bh1 = b2f(sBH[bhbase + 2 * kt + 1]);

        #pragma unroll
        for (int kvt = 0; kvt < 2; ++kvt) {
            f32x16 s = {};
            __builtin_amdgcn_s_setprio(1);
            #pragma unroll
            for (int ck = 0; ck < 4; ++ck) {
                s16x8 kf = *(const s16x8*)(sKr + (kvt * 32 + l31) * 72 + ck * 16 + hi * 8);
                s = __builtin_amdgcn_mfma_f32_32x32x16_bf16(kf, qfr[ck], s, 0, 0, 0);
            }
            __builtin_amdgcn_s_setprio(0);
            const float bh = kvt ? bh1 : bh0;

            u32 pw[8];
            #pragma unroll
            for (int m = 0; m < 8; ++m) {
                float p0 = __builtin_amdgcn_exp2f(s[2*m]   + bh + bwv[(2*m)>>2][(2*m)&3]);
                float p1 = __builtin_amdgcn_exp2f(s[2*m+1] + bh + bwv[(2*m+1)>>2][(2*m+1)&3]);
                lsum += p0 + p1;
                pw[m] = (u32)f2b(p0) | ((u32)f2b(p1) << 16);
            }

            __builtin_amdgcn_s_setprio(1);
            #pragma unroll
            for (int cc = 0; cc < 2; ++cc) {
                i32x2 s02 = __builtin_amdgcn_permlane32_swap((int)pw[cc*4+0], (int)pw[cc*4+2], false, false);
                i32x2 s13 = __builtin_amdgcn_permlane32_swap((int)pw[cc*4+1], (int)pw[cc*4+3], false, false);
                u32x4 pau;
                pau.x = (u32)s02.x; pau.y = (u32)s13.x;
                pau.z = (u32)s02.y; pau.w = (u32)s13.y;
                s16x8 pa = *reinterpret_cast<s16x8*>(&pau);
                const int kc = kvt * 2 + cc;
                #pragma unroll
                for (int dt = 0; dt < 2; ++dt) {
                    s16x8 vf = *(const s16x8*)(sVr + (dt * 32 + l31) * 72 + kc * 16 + hi * 8);
                    Oacc[dt] = __builtin_amdgcn_mfma_f32_32x32x16_bf16(pa, vf, Oacc[dt], 0, 0, 0);
                }
            }
            __builtin_amdgcn_s_setprio(0);
        }

        if (kt < 15) {
            *(s16x8*)(skwN)     = kr0;
            *(s16x8*)(skwN + 8) = kr1;
            *(s16x8*)(svwN)     = vr0;
            *(s16x8*)(svwN + 8) = vr1;
        }
        asm volatile("s_waitcnt lgkmcnt(0)" ::: "memory");
        __builtin_amdgcn_s_barrier();
        __builtin_amdgcn_sched_barrier(0);
    };

    for (int k2 = 0; k2 < 8; ++k2) {
        body(2 * k2,     sK0, sVt0, skw1, svw1);
        body(2 * k2 + 1, sK1, sVt1, skw0, svw0);
    }

    float lsumF = lsum + __shfl_xor(lsum, 32);
    float linv[16];
    #pragma unroll
    for (int r = 0; r < 16; ++r) {
        const int qloc = (r & 3) + 8 * (r >> 2) + 4 * hi;
        linv[r] = 1.0f / __shfl(lsumF, qloc);
    }

    const int n_img = b / NH_;
    const int head  = b % NH_;
    #pragma unroll
    for (int dt = 0; dt < 2; ++dt) {
        #pragma unroll
        for (int r = 0; r < 16; ++r) {
            const int qloc = (r & 3) + 8 * (r >> 2) + 4 * hi;
            const int qg = qbase + qw + qloc;
            ob[(size_t)(n_img * HW_ + qg) * C_ + head * HD_ + dt * 32 + l31] =
                f2b(Oacc[dt][r] * linv[r]);
        }
    }
}

extern "C" void kernel_launch(void* const* d_in, const int* in_sizes, int n_in,
                              void* d_out, int out_size, void* d_ws, size_t ws_size,
                              hipStream_t stream) {
    const float* x      = (const float*)d_in[0];
    const float* w_qkv  = (const float*)d_in[1];
    const float* b_qkv  = (const float*)d_in[2];
    const float* w_proj = (const float*)d_in[3];
    const float* b_proj = (const float*)d_in[4];
    const float* rel_h  = (const float*)d_in[5];
    const float* rel_w  = (const float*)d_in[6];
    float* out = (float*)d_out;

    const size_t seg = (size_t)B_ * HW_ * HD_;   // 6,291,456
    char* p = (char*)d_ws;
    u16* xb     = (u16*)p;  p += seg * 2;
    u16* wqkvT  = (u16*)p;  p += (size_t)C3_ * C_ * 2;
    u16* wprojT = (u16*)p;  p += (size_t)C_ * C_ * 2;
    u16* qb     = (u16*)p;  p += seg * 2;
    u16* kbf    = (u16*)p;  p += seg * 2;
    u16* vtb    = (u16*)p;  p += seg * 2;
    u16* ob     = (u16*)p;  p += seg * 2;
    u16* Fg     = (u16*)p;  p += seg * 2;
    u16* Eg     = (u16*)p;  p += seg * 2;

    cvt_bf16<<<2048, 256, 0, stream>>>(x, xb, (int)(seg / 4));
    tcvt_bf16<<<dim3(C3_ / 64, C_ / 64), 256, 0, stream>>>(w_qkv, wqkvT, C_, C3_);
    tcvt_bf16<<<dim3(C_ / 64, C_ / 64), 256, 0, stream>>>(w_proj, wprojT, C_, C_);

    gemm_qkv<<<1152, 256, 49152, stream>>>(xb, wqkvT, b_qkv, qb, kbf, vtb);
    ef_gemm<<<768, 256, 0, stream>>>(qb, rel_h, rel_w, Fg, Eg);
    attn_mfma<<<768, 256, 45568, stream>>>(qb, kbf, vtb, Fg, Eg, ob);
    gemm_proj<<<384, 256, 49152, stream>>>(ob, wprojT, b_proj, out);
}

// Round 17
// 141.078 us; speedup vs baseline: 4.6412x; 1.0122x over previous
//
#include <hip/hip_runtime.h>
#include <hip/hip_bf16.h>

#define N_    8
#define H_    32
#define W_    32
#define C_    768
#define NH_   12
#define HD_   64
#define B_    96      // N_*NH_
#define HW_   1024
#define C3_   2304
#define SCALE_ 0.125f
#define LOG2E_ 1.4426950408889634f

typedef __attribute__((ext_vector_type(4))) float f32x4;
typedef __attribute__((ext_vector_type(16))) float f32x16;
typedef __attribute__((ext_vector_type(8))) short s16x8;
typedef __attribute__((ext_vector_type(2))) int i32x2;
typedef __attribute__((ext_vector_type(2))) unsigned int u32x2;
typedef __attribute__((ext_vector_type(4))) unsigned int u32x4;
typedef unsigned short u16;
typedef unsigned int u32;

__device__ inline u16 f2b(float x) {
    __hip_bfloat16 h = __float2bfloat16(x);
    return *reinterpret_cast<u16*>(&h);
}
__device__ inline float b2f(u16 x) {
    u32 u = ((u32)x) << 16;
    return *reinterpret_cast<float*>(&u);
}
// packed bf16 convert: lo = RNE(a), hi = RNE(b)  (T12 recipe, no builtin)
__device__ __forceinline__ u32 cvtpk(float a, float b) {
    u32 r;
    asm("v_cvt_pk_bf16_f32 %0, %1, %2" : "=v"(r) : "v"(a), "v"(b));
    return r;
}

__device__ __forceinline__ void gld_lds16(const void* g, void* l) {
    __builtin_amdgcn_global_load_lds(
        (const __attribute__((address_space(1))) u32*)g,
        (__attribute__((address_space(3))) u32*)l, 16, 0, 0);
}

// ---------------------------------------------------------------------------
// convert fp32 -> bf16 (vectorized, grid-stride)
// ---------------------------------------------------------------------------
__global__ __launch_bounds__(256) void cvt_bf16(const float* __restrict__ in,
                                                u16* __restrict__ out, int n4) {
    for (int i = blockIdx.x * blockDim.x + threadIdx.x; i < n4; i += gridDim.x * blockDim.x) {
        float4 v = ((const float4*)in)[i];
        ushort4 o;
        o.x = f2b(v.x); o.y = f2b(v.y); o.z = f2b(v.z); o.w = f2b(v.w);
        ((ushort4*)out)[i] = o;
    }
}

// ---------------------------------------------------------------------------
// transpose-convert: in [K][N] fp32 -> out [N][K] bf16, 64x64 tiles
// ---------------------------------------------------------------------------
__global__ __launch_bounds__(256) void tcvt_bf16(const float* __restrict__ in,
                                                 u16* __restrict__ out, int K, int N) {
    __shared__ u16 tile[64][72];
    const int t = threadIdx.x;
    const int k0 = blockIdx.y * 64, n0 = blockIdx.x * 64;
    const int r = t >> 2, c4 = (t & 3) * 16;
    #pragma unroll
    for (int u = 0; u < 4; ++u) {
        float4 v = *(const float4*)(in + (size_t)(k0 + r) * N + n0 + c4 + u * 4);
        tile[c4 + u*4 + 0][r] = f2b(v.x);
        tile[c4 + u*4 + 1][r] = f2b(v.y);
        tile[c4 + u*4 + 2][r] = f2b(v.z);
        tile[c4 + u*4 + 3][r] = f2b(v.w);
    }
    __syncthreads();
    #pragma unroll
    for (int u = 0; u < 2; ++u) {
        s16x8 v;
        #pragma unroll
        for (int e = 0; e < 8; ++e) v[e] = (short)tile[r][c4 + u*8 + e];
        *(s16x8*)(out + (size_t)(n0 + r) * K + k0 + c4 + u*8) = v;
    }
}

// ---------------------------------------------------------------------------
// GEMM core, 3-DEEP pipeline (T3/T4-lite): 128x128 tile, BK=32, 4 waves 2x2.
// Loads for tile kt+2 issued at iter kt; barrier waits s_waitcnt vmcnt(4).
// Raw s_barrier + lgkmcnt(0) + sched_barrier(0).  XCD-bijective swizzle.
// Dynamic LDS: 3x(8KB A + 8KB B) = 49152 B.  K=768 (24 steps).
// ---------------------------------------------------------------------------
#define G3_ISSUE(KB, BUF)                                                            \
    gld_lds16(gA0 + (KB), sAb + (BUF) * 4096 + w * 512);                             \
    gld_lds16(gA1 + (KB), sAb + (BUF) * 4096 + (w + 4) * 512);                       \
    gld_lds16(gB0 + (KB), sBb + (BUF) * 4096 + w * 512);                             \
    gld_lds16(gB1 + (KB), sBb + (BUF) * 4096 + (w + 4) * 512);

#define G3_COMP(BUF)                                                                 \
    {                                                                                \
        const u16* pa = sAb + (BUF) * 4096 + (wm * 64 + l15) * 32 + lg * 8;          \
        const u16* pb = sBb + (BUF) * 4096 + (wn * 64 + l15) * 32 + lg * 8;          \
        s16x8 afr[4], bfr[4];                                                        \
        _Pragma("unroll")                                                            \
        for (int i = 0; i < 4; ++i) {                                                \
            afr[i] = *(const s16x8*)(pa + i * 512);                                  \
            bfr[i] = *(const s16x8*)(pb + i * 512);                                  \
        }                                                                            \
        _Pragma("unroll")                                                            \
        for (int i = 0; i < 4; ++i)                                                  \
            _Pragma("unroll")                                                        \
            for (int j = 0; j < 4; ++j)                                              \
                acc[i][j] = __builtin_amdgcn_mfma_f32_16x16x32_bf16(afr[i], bfr[j],  \
                                                                    acc[i][j], 0, 0, 0); \
    }

#define G3_BAR4                                                                      \
    asm volatile("s_waitcnt vmcnt(4) lgkmcnt(0)" ::: "memory");                      \
    __builtin_amdgcn_s_barrier();                                                    \
    __builtin_amdgcn_sched_barrier(0);

#define G3_BAR0                                                                      \
    asm volatile("s_waitcnt vmcnt(0) lgkmcnt(0)" ::: "memory");                      \
    __builtin_amdgcn_s_barrier();                                                    \
    __builtin_amdgcn_sched_barrier(0);

#define GEMM_CORE3(A_, Bt_, NT_)                                                     \
    extern __shared__ char smem[];                                                   \
    u16* sAb = (u16*)smem;                   /* 3 x [128*32] u16 */                  \
    u16* sBb = (u16*)(smem + 24576);         /* 3 x [128*32] u16 */                  \
    const int t = threadIdx.x;                                                       \
    const int lane = t & 63;                                                         \
    const int w = t >> 6;                                                            \
    const int wm = w >> 1, wn = w & 1;                                               \
    const int l15 = lane & 15, lg = lane >> 4;                                       \
    const int per = (int)gridDim.x >> 3;                                             \
    const int swz = ((int)blockIdx.x & 7) * per + ((int)blockIdx.x >> 3);            \
    const int nbase = (swz % (NT_)) * 128;                                           \
    const int mbase = (swz / (NT_)) * 128;                                           \
    const int srow = lane >> 2;                                                      \
    const int sslot = lane & 3;                                                      \
    const u16* gA0 = (A_) + (size_t)(mbase + w * 16 + srow) * 768 + sslot * 8;       \
    const u16* gA1 = gA0 + (size_t)64 * 768;                                         \
    const u16* gB0 = (Bt_) + (size_t)(nbase + w * 16 + srow) * 768 + sslot * 8;      \
    const u16* gB1 = gB0 + (size_t)64 * 768;                                         \
    f32x4 acc[4][4] = {};                                                            \
    G3_ISSUE(0, 0)                                                                   \
    G3_ISSUE(32, 1)                                                                  \
    G3_BAR4                                                                          \
    for (int k3 = 0; k3 < 7; ++k3) {                                                 \
        const int kb = k3 * 96;                                                      \
        G3_ISSUE(kb + 64, 2)  G3_COMP(0)  G3_BAR4                                    \
        G3_ISSUE(kb + 96, 0)  G3_COMP(1)  G3_BAR4                                    \
        G3_ISSUE(kb + 128, 1) G3_COMP(2)  G3_BAR4                                    \
    }                                                                                \
    G3_ISSUE(736, 2) G3_COMP(0) G3_BAR4                                              \
    G3_COMP(1) G3_BAR0                                                               \
    G3_COMP(2) G3_BAR0

// qkv = x @ w_qkv + b_qkv; outputs bf16 q/k [b][p][64], v transposed
// [b][64][p]; coalesced epilogue through LDS tile T[128][136].
__global__ __launch_bounds__(256) void gemm_qkv(const u16* __restrict__ A,
                                                const u16* __restrict__ Bt,
                                                const float* __restrict__ bias,
                                                u16* __restrict__ qout,
                                                u16* __restrict__ kout,
                                                u16* __restrict__ vout) {
    GEMM_CORE3(A, Bt, 18)
    u16* T = (u16*)smem;

    const int which = nbase / C_;
    const int head0 = (nbase % C_) >> 6;
    const int n_img = mbase >> 10;
    const int pbase = mbase & 1023;

    if (which < 2) {
        #pragma unroll
        for (int i = 0; i < 4; ++i)
            #pragma unroll
            for (int r = 0; r < 4; ++r) {
                const int lm = wm * 64 + i * 16 + lg * 4 + r;
                #pragma unroll
                for (int j = 0; j < 4; ++j) {
                    const int lc = wn * 64 + j * 16 + l15;
                    T[lm * 136 + lc] = f2b(acc[i][j][r] + bias[nbase + lc]);
                }
            }
    } else {
        #pragma unroll
        for (int i = 0; i < 4; ++i)
            #pragma unroll
            for (int r = 0; r < 4; ++r) {
                const int lm = wm * 64 + i * 16 + lg * 4 + r;
                #pragma unroll
                for (int j = 0; j < 4; ++j) {
                    const int lc = wn * 64 + j * 16 + l15;
                    T[lc * 136 + lm] = f2b(acc[i][j][r] + bias[nbase + lc]);
                }
            }
    }
    __syncthreads();

    if (which < 2) {
        u16* dst = (which == 0) ? qout : kout;
        #pragma unroll
        for (int pass = 0; pass < 4; ++pass) {
            const int lm = pass * 32 + (t >> 3);
            #pragma unroll
            for (int hh = 0; hh < 2; ++hh) {
                s16x8 row = *(const s16x8*)(T + lm * 136 + hh * 64 + (t & 7) * 8);
                const size_t bidx = (size_t)(n_img * NH_ + head0 + hh);
                *(s16x8*)(dst + (bidx * HW_ + pbase + lm) * HD_ + (t & 7) * 8) = row;
            }
        }
    } else {
        #pragma unroll
        for (int pass = 0; pass < 8; ++pass) {
            const int lc = pass * 16 + (t >> 4);
            s16x8 row = *(const s16x8*)(T + lc * 136 + (t & 15) * 8);
            const int hh = lc >> 6, d = lc & 63;
            const size_t bidx = (size_t)(n_img * NH_ + head0 + hh);
            *(s16x8*)(vout + bidx * (size_t)(HW_ * HD_) + (size_t)d * HW_ + pbase + (t & 15) * 8) = row;
        }
    }
}

// out = o @ w_proj + b_proj, fp32 out
__global__ __launch_bounds__(256) void gemm_proj(const u16* __restrict__ A,
                                                 const u16* __restrict__ Bt,
                                                 const float* __restrict__ bias,
                                                 float* __restrict__ out) {
    GEMM_CORE3(A, Bt, 6)
    const int mrow0 = mbase + wm * 64 + lg * 4;
    #pragma unroll
    for (int i = 0; i < 4; ++i) {
        #pragma unroll
        for (int r = 0; r < 4; ++r) {
            const int m = mrow0 + i * 16 + r;
            #pragma unroll
            for (int j = 0; j < 4; ++j) {
                const int n = nbase + wn * 64 + j * 16 + l15;
                out[(size_t)m * C_ + n] = acc[i][j][r] + bias[n];
            }
        }
    }
}

// ---------------------------------------------------------------------------
// ef_gemm: F = Q @ rel_h^T, E = Q @ rel_w^T (x LOG2E), bf16 out [98304][64].
// ---------------------------------------------------------------------------
__global__ __launch_bounds__(256) void ef_gemm(const u16* __restrict__ qb_,
                                               const float* __restrict__ rel_h,
                                               const float* __restrict__ rel_w,
                                               u16* __restrict__ Fg,
                                               u16* __restrict__ Eg) {
    const int t = threadIdx.x;
    const int lane = t & 63;
    const int w = t >> 6;
    const int l31 = lane & 31;
    const int hi  = lane >> 5;
    const size_t Mrow = (size_t)blockIdx.x * 128 + w * 32 + l31;

    s16x8 qb[4];
    {
        const u16* qrow = qb_ + Mrow * HD_;
        #pragma unroll
        for (int ck = 0; ck < 4; ++ck)
            qb[ck] = *(const s16x8*)(qrow + ck * 16 + hi * 8);
    }

    #pragma unroll
    for (int tb = 0; tb < 2; ++tb) {
        const float* R = tb ? rel_w : rel_h;
        u16* og = (tb ? Eg : Fg) + Mrow * 64;
        #pragma unroll
        for (int hh = 0; hh < 2; ++hh) {
            const int dr = hh * 32 + l31;
            const float* rrow = R + (size_t)(dr > 62 ? 62 : dr) * HD_;
            f32x16 acc = {};
            #pragma unroll
            for (int ck = 0; ck < 4; ++ck) {
                float4 r0 = *(const float4*)(rrow + ck * 16 + hi * 8);
                float4 r1 = *(const float4*)(rrow + ck * 16 + hi * 8 + 4);
                s16x8 af;
                af[0] = (short)f2b(r0.x * LOG2E_); af[1] = (short)f2b(r0.y * LOG2E_);
                af[2] = (short)f2b(r0.z * LOG2E_); af[3] = (short)f2b(r0.w * LOG2E_);
                af[4] = (short)f2b(r1.x * LOG2E_); af[5] = (short)f2b(r1.y * LOG2E_);
                af[6] = (short)f2b(r1.z * LOG2E_); af[7] = (short)f2b(r1.w * LOG2E_);
                acc = __builtin_amdgcn_mfma_f32_32x32x16_bf16(af, qb[ck], acc, 0, 0, 0);
            }
            #pragma unroll
            for (int u = 0; u < 4; ++u) {
                u32x2 pkd;
                pkd.x = cvtpk(acc[4*u+0], acc[4*u+1]);
                pkd.y = cvtpk(acc[4*u+2], acc[4*u+3]);
                *(u32x2*)(og + hh * 32 + u * 8 + 4 * hi) = pkd;
            }
        }
    }
}

// ---------------------------------------------------------------------------
// attn — r13 main loop (dbuf, one raw barrier/tile, lgkmcnt-only wait) +
// E/F bias tables + T5 setprio + NEW:
//  * P pack via v_cvt_pk_bf16_f32 (8 cvt_pk/kvt replace ~48 scalar-cast ops)
//  * MFMA row-sum: Osum = mfma(pa, ONES, Osum) — denominator on the matrix
//    pipe, layout identical to Oacc -> linv[r] = 1/Osum[r], no shuffles.
// LDS: sBH u16[128][34] @0; sK0 @8704 sK1 @17920 sVt0 @27136 sVt1 @36352
// -> 45568 B, 3 blocks/CU.
// ---------------------------------------------------------------------------
__global__ __launch_bounds__(256) void attn_mfma(const u16* __restrict__ qb_,
                                                 const u16* __restrict__ kbf,
                                                 const u16* __restrict__ vtb,
                                                 const u16* __restrict__ Fg,
                                                 const u16* __restrict__ Eg,
                                                 u16* __restrict__ ob) {
    extern __shared__ char smem[];
    u16*   sBH  = (u16*)smem;
    u16*   sK0  = (u16*)(smem + 8704);
    u16*   sK1  = (u16*)(smem + 17920);
    u16*   sVt0 = (u16*)(smem + 27136);
    u16*   sVt1 = (u16*)(smem + 36352);

    const int t = threadIdx.x;
    const int lane = t & 63;
    const int w = t >> 6;
    const int l31 = lane & 31;
    const int hi  = lane >> 5;
    const int qw  = w * 32;

    const int bid = blockIdx.x;
    const int swz = (bid & 7) * 96 + (bid >> 3);
    const int b = swz >> 3;
    const int qbase = (swz & 7) * 128;

    s16x8 qfr[4];
    {
        const u16* qrow = qb_ + ((size_t)b * HW_ + qbase + qw + l31) * HD_;
        #pragma unroll
        for (int ck = 0; ck < 4; ++ck) {
            s16x8 qv = *(const s16x8*)(qrow + ck * 16 + hi * 8);
            #pragma unroll
            for (int e = 0; e < 8; ++e)
                qfr[ck][e] = (short)f2b(b2f((u16)qv[e]) * (SCALE_ * LOG2E_));
        }
    }

    {
        const u16* Fb = Fg + (size_t)b * HW_ * 64;
        for (int idv = t; idv < 4096; idv += 256) {
            const int row = idv >> 5;
            const int kh  = idv & 31;
            const int qg  = qbase + row;
            sBH[row * 34 + kh] = Fb[(size_t)qg * 64 + (qg >> 5) + 31 - kh];
        }
    }

    f32x4 bwv[4];
    {
        const int qmy = qbase + qw + l31;
        const u16* Erow = Eg + (size_t)(b * HW_ + qmy) * 64;
        #pragma unroll
        for (int m = 0; m < 4; ++m)
            #pragma unroll
            for (int j = 0; j < 4; ++j)
                bwv[m][j] = b2f(Erow[l31 + 31 - (m * 8 + 4 * hi + j)]);
    }

    const int srow = t >> 2;
    const int sc0  = (t & 3) * 16;
    const u16* kg = kbf + ((size_t)b * HW_ + srow) * HD_ + sc0;
    const u16* vg = vtb + (size_t)b * HD_ * HW_ + (size_t)srow * HW_ + sc0;
    u16* skw0 = sK0  + srow * 72 + sc0;
    u16* skw1 = sK1  + srow * 72 + sc0;
    u16* svw0 = sVt0 + srow * 72 + sc0;
    u16* svw1 = sVt1 + srow * 72 + sc0;

    s16x8 kr0 = *(const s16x8*)(kg);
    s16x8 kr1 = *(const s16x8*)(kg + 8);
    s16x8 vr0 = *(const s16x8*)(vg);
    s16x8 vr1 = *(const s16x8*)(vg + 8);
    *(s16x8*)(skw0)     = kr0;
    *(s16x8*)(skw0 + 8) = kr1;
    *(s16x8*)(svw0)     = vr0;
    *(s16x8*)(svw0 + 8) = vr1;
    __syncthreads();

    f32x16 Oacc[2] = {};
    f32x16 Osum = {};
    const u32x4 onesu = {0x3F803F80u, 0x3F803F80u, 0x3F803F80u, 0x3F803F80u};
    const s16x8 ones = *reinterpret_cast<const s16x8*>(&onesu);
    const int bhbase = (qw + l31) * 34;

    auto body = [&](int kt, const u16* sKr, const u16* sVr, u16* skwN, u16* svwN) {
        if (kt < 15) {
            const u16* kn = kg + (size_t)(kt + 1) * 64 * HD_;
            kr0 = *(const s16x8*)(kn);
            kr1 = *(const s16x8*)(kn + 8);
            const u16* vn = vg + (size_t)(kt + 1) * 64;
            vr0 = *(const s16x8*)(vn);
            vr1 = *(const s16x8*)(vn + 8);
        }

        const float bh0 = b2f(sBH[bhbase + 2 * kt]);
        const float bh1 = b2f(sBH[bhbase + 2 * kt + 1]);

        #pragma unroll
        for (int kvt = 0; kvt < 2; ++kvt) {
            f32x16 s = {};
            __builtin_amdgcn_s_setprio(1);
            #pragma unroll
            for (int ck = 0; ck < 4; ++ck) {
                s16x8 kf = *(const s16x8*)(sKr + (kvt * 32 + l31) * 72 + ck * 16 + hi * 8);
                s = __builtin_amdgcn_mfma_f32_32x32x16_bf16(kf, qfr[ck], s, 0, 0, 0);
            }
            __builtin_amdgcn_s_setprio(0);
            const float bh = kvt ? bh1 : bh0;

            u32 pw[8];
            #pragma unroll
            for (int m = 0; m < 8; ++m) {
                float p0 = __builtin_amdgcn_exp2f(s[2*m]   + bh + bwv[(2*m)>>2][(2*m)&3]);
                float p1 = __builtin_amdgcn_exp2f(s[2*m+1] + bh + bwv[(2*m+1)>>2][(2*m+1)&3]);
                pw[m] = cvtpk(p0, p1);
            }

            __builtin_amdgcn_s_setprio(1);
            #pragma unroll
            for (int cc = 0; cc < 2; ++cc) {
                i32x2 s02 = __builtin_amdgcn_permlane32_swap((int)pw[cc*4+0], (int)pw[cc*4+2], false, false);
                i32x2 s13 = __builtin_amdgcn_permlane32_swap((int)pw[cc*4+1], (int)pw[cc*4+3], false, false);
                u32x4 pau;
                pau.x = (u32)s02.x; pau.y = (u32)s13.x;
                pau.z = (u32)s02.y; pau.w = (u32)s13.y;
                s16x8 pa = *reinterpret_cast<s16x8*>(&pau);
                const int kc = kvt * 2 + cc;
                #pragma unroll
                for (int dt = 0; dt < 2; ++dt) {
                    s16x8 vf = *(const s16x8*)(sVr + (dt * 32 + l31) * 72 + kc * 16 + hi * 8);
                    Oacc[dt] = __builtin_amdgcn_mfma_f32_32x32x16_bf16(pa, vf, Oacc[dt], 0, 0, 0);
                }
                Osum = __builtin_amdgcn_mfma_f32_32x32x16_bf16(pa, ones, Osum, 0, 0, 0);
            }
            __builtin_amdgcn_s_setprio(0);
        }

        if (kt < 15) {
            *(s16x8*)(skwN)     = kr0;
            *(s16x8*)(skwN + 8) = kr1;
            *(s16x8*)(svwN)     = vr0;
            *(s16x8*)(svwN + 8) = vr1;
        }
        asm volatile("s_waitcnt lgkmcnt(0)" ::: "memory");
        __builtin_amdgcn_s_barrier();
        __builtin_amdgcn_sched_barrier(0);
    };

    for (int k2 = 0; k2 < 8; ++k2) {
        body(2 * k2,     sK0, sVt0, skw1, svw1);
        body(2 * k2 + 1, sK1, sVt1, skw0, svw0);
    }

    // ---- epilogue: Osum[r] = full row-sum for the same q as Oacc[dt][r]
    const int n_img = b / NH_;
    const int head  = b % NH_;
    #pragma unroll
    for (int dt = 0; dt < 2; ++dt) {
        #pragma unroll
        for (int r = 0; r < 16; ++r) {
            const int qloc = (r & 3) + 8 * (r >> 2) + 4 * hi;
            const int qg = qbase + qw + qloc;
            ob[(size_t)(n_img * HW_ + qg) * C_ + head * HD_ + dt * 32 + l31] =
                f2b(Oacc[dt][r] / Osum[r]);
        }
    }
}

extern "C" void kernel_launch(void* const* d_in, const int* in_sizes, int n_in,
                              void* d_out, int out_size, void* d_ws, size_t ws_size,
                              hipStream_t stream) {
    const float* x      = (const float*)d_in[0];
    const float* w_qkv  = (const float*)d_in[1];
    const float* b_qkv  = (const float*)d_in[2];
    const float* w_proj = (const float*)d_in[3];
    const float* b_proj = (const float*)d_in[4];
    const float* rel_h  = (const float*)d_in[5];
    const float* rel_w  = (const float*)d_in[6];
    float* out = (float*)d_out;

    const size_t seg = (size_t)B_ * HW_ * HD_;   // 6,291,456
    char* p = (char*)d_ws;
    u16* xb     = (u16*)p;  p += seg * 2;
    u16* wqkvT  = (u16*)p;  p += (size_t)C3_ * C_ * 2;
    u16* wprojT = (u16*)p;  p += (size_t)C_ * C_ * 2;
    u16* qb     = (u16*)p;  p += seg * 2;
    u16* kbf    = (u16*)p;  p += seg * 2;
    u16* vtb    = (u16*)p;  p += seg * 2;
    u16* ob     = (u16*)p;  p += seg * 2;
    u16* Fg     = (u16*)p;  p += seg * 2;
    u16* Eg     = (u16*)p;  p += seg * 2;

    cvt_bf16<<<2048, 256, 0, stream>>>(x, xb, (int)(seg / 4));
    tcvt_bf16<<<dim3(C3_ / 64, C_ / 64), 256, 0, stream>>>(w_qkv, wqkvT, C_, C3_);
    tcvt_bf16<<<dim3(C_ / 64, C_ / 64), 256, 0, stream>>>(w_proj, wprojT, C_, C_);

    gemm_qkv<<<1152, 256, 49152, stream>>>(xb, wqkvT, b_qkv, qb, kbf, vtb);
    ef_gemm<<<768, 256, 0, stream>>>(qb, rel_h, rel_w, Fg, Eg);
    attn_mfma<<<768, 256, 45568, stream>>>(qb, kbf, vtb, Fg, Eg, ob);
    gemm_proj<<<384, 256, 49152, stream>>>(ob, wprojT, b_proj, out);
}